// Round 2
// baseline (257.631 us; speedup 1.0000x reference)
//
#include <hip/hip_runtime.h>
#include <hip/hip_bf16.h>
#include <math.h>

#define B_IMG   2
#define N_PROP  2000
#define N_GT    16
#define NPROPS  2016        // N_PROP + N_GT
#define C_FEAT  256
#define H_FEAT  128
#define W_FEAT  128
#define HWF     (H_FEAT*W_FEAT)
#define POOL    7
#define BPI     512
#define NPOSMAX 128
#define NSEL    (B_IMG*BPI)     // 1024
#define K1      (C_FEAT*POOL*POOL)  // 12544
#define K1P     12800           // K1 padded to 16*800
#define HID     1024
#define NHEAD   14
#define SPLITK1 8               // KC = 1600 (pipelined GEMM1)
#define SPLITK2 8               // KC = 128

typedef short bf16x8f __attribute__((ext_vector_type(8)));
typedef float f32x4f  __attribute__((ext_vector_type(4)));
typedef short short4v __attribute__((ext_vector_type(4)));

// ---------------------------------------------------------------- threefry
__device__ __forceinline__ void threefry2x32(unsigned k0, unsigned k1,
                                             unsigned& x0, unsigned& x1) {
  unsigned ks[3] = {k0, k1, k0 ^ k1 ^ 0x1BD11BDAu};
  const int R0[4] = {13, 15, 26, 6};
  const int R1[4] = {17, 29, 16, 24};
  x0 += ks[0]; x1 += ks[1];
#pragma unroll
  for (int g = 0; g < 5; g++) {
    const int* rot = (g & 1) ? R1 : R0;
#pragma unroll
    for (int r = 0; r < 4; r++) {
      x0 += x1;
      x1 = (x1 << rot[r]) | (x1 >> (32 - rot[r]));
      x1 ^= x0;
    }
    x0 += ks[(g + 1) % 3];
    x1 += ks[(g + 2) % 3] + (unsigned)(g + 1);
  }
}

// ---------------- mega-prologue: sample(2) | transpose(2048) | castT1(3136)
//                  | castT0(256) | pad(512)  — blockIdx-range dispatch
#define PRE_SAMPLE   2
#define PRE_TRANS    (PRE_SAMPLE + 2048)
#define PRE_CAST1    (PRE_TRANS + 3136)
#define PRE_CAST0    (PRE_CAST1 + 256)
#define PRE_TOTAL    (PRE_CAST0 + 512)

__global__ __launch_bounds__(256) void k_pre(const float* __restrict__ proposals,
                                             const float* __restrict__ gt_boxes,
                                             const int* __restrict__ gt_labels,
                                             const float* __restrict__ features,
                                             const float* __restrict__ w1,
                                             const float* __restrict__ w2,
                                             float* __restrict__ prio,
                                             int* __restrict__ plab,
                                             int* __restrict__ matches,
                                             __hip_bfloat16* __restrict__ featT,
                                             __hip_bfloat16* __restrict__ W1T,
                                             __hip_bfloat16* __restrict__ W2T,
                                             __hip_bfloat16* __restrict__ Xb) {
  __shared__ __align__(16) char smem[20800];
  int bid = blockIdx.x;
  int tid = threadIdx.x;
  if (bid < PRE_SAMPLE) {
    // ---------------- sample: rand + IoU match + positive-rank priorities
    float* rs    = (float*)smem;              // 2016
    float* pos_r = (float*)(smem + 8064);     // 2016
    short* pos_i = (short*)(smem + 16128);    // 2016
    float* gtb   = (float*)(smem + 20160);    // 64
    int*   gtl   = (int*)(smem + 20416);      // 16
    int*   cnt   = (int*)(smem + 20480);
    int b = bid;
    int base = b * NPROPS;
    if (tid == 0) *cnt = 0;
    if (tid < N_GT * 4) gtb[tid] = gt_boxes[b * N_GT * 4 + tid];
    if (tid < N_GT) gtl[tid] = gt_labels[b * N_GT + tid];
    __syncthreads();
    for (int i = tid; i < NPROPS; i += 256) {
      unsigned x0 = 0u, x1 = (unsigned)(base + i);
      threefry2x32(0u, 42u, x0, x1);
      unsigned bits = x0 ^ x1;
      float r = __uint_as_float((bits >> 9) | 0x3F800000u) - 1.0f;
      rs[i] = r;
      float p0, p1, p2, p3;
      if (i < N_PROP) {
        const float4 v = *(const float4*)(proposals + ((size_t)b * N_PROP + i) * 4);
        p0 = v.x; p1 = v.y; p2 = v.z; p3 = v.w;
      } else {
        const float* g = &gtb[(i - N_PROP) * 4];
        p0 = g[0]; p1 = g[1]; p2 = g[2]; p3 = g[3];
      }
      float a2 = (p2 - p0) * (p3 - p1);
      float best = -1.0f; int bg = 0;
#pragma unroll
      for (int g = 0; g < N_GT; g++) {
        float g0 = gtb[g*4], g1 = gtb[g*4+1], g2 = gtb[g*4+2], g3 = gtb[g*4+3];
        float a1 = (g2 - g0) * (g3 - g1);
        float wx = fmaxf(fminf(g2, p2) - fmaxf(g0, p0), 0.0f);
        float wy = fmaxf(fminf(g3, p3) - fmaxf(g1, p1), 0.0f);
        float inter = wx * wy;
        float iou = inter / (a1 + a2 - inter);
        if (iou > best) { best = iou; bg = g; }
      }
      matches[base + i] = bg;
      int lab = (best < 0.5f) ? 0 : gtl[bg];
      plab[base + i] = lab;
      if (lab > 0) {
        int s = atomicAdd(cnt, 1);
        pos_i[s] = (short)i; pos_r[s] = r;
      }
    }
    __syncthreads();
    int P = *cnt;
    for (int s = tid; s < P; s += 256) {
      int i = pos_i[s]; float ri = pos_r[s];
      int ch = 0;
      for (int j = 0; j < P; j++) {
        float rj = pos_r[j]; int ij = pos_i[j];
        ch += (rj > ri || (rj == ri && ij < i)) ? 1 : 0;
      }
      rs[i] = (ch < NPOSMAX) ? (ri + 2.0f) : -1000000000.0f;
    }
    __syncthreads();
    for (int i = tid; i < NPROPS; i += 256) prio[base + i] = rs[i];
  } else if (bid < PRE_TRANS) {
    // ---------------- NCHW -> NHWC bf16, 64x64 tiles
    float (*tile)[65] = (float(*)[65])smem;
    int t = bid - PRE_SAMPLE;
    int b = t >> 10;
    int rem = t & 1023;
    int c0 = (rem >> 8) * 64;
    int s0 = (rem & 255) * 64;
    const float* src = features + (size_t)b * C_FEAT * HWF;
    __hip_bfloat16* dst = featT + (size_t)b * HWF * C_FEAT;
    int hw4 = (tid & 15) * 4, cr = tid >> 4;
#pragma unroll
    for (int p = 0; p < 4; p++) {
      int c = cr + p * 16;
      float4 v = *(const float4*)(src + (size_t)(c0 + c) * HWF + s0 + hw4);
      tile[hw4 + 0][c] = v.x; tile[hw4 + 1][c] = v.y;
      tile[hw4 + 2][c] = v.z; tile[hw4 + 3][c] = v.w;
    }
    __syncthreads();
    int c4 = (tid & 15) * 4, hr = tid >> 4;
#pragma unroll
    for (int p = 0; p < 4; p++) {
      int hw = hr + p * 16;
      __hip_bfloat16 o[4] = {__float2bfloat16(tile[hw][c4]), __float2bfloat16(tile[hw][c4+1]),
                             __float2bfloat16(tile[hw][c4+2]), __float2bfloat16(tile[hw][c4+3])};
      *(short4v*)(dst + (size_t)(s0 + hw) * C_FEAT + c0 + c4) = *(short4v*)o;
    }
  } else if (bid < PRE_CAST1) {
    // ---------------- w1 cast: fp32 [c*49+p][N] -> bf16 [N][p*256+c]
    float (*tile)[65] = (float(*)[65])smem;
    int t = bid - PRE_TRANS;
    int p = t >> 6;
    int rem = t & 63;
    int c0 = (rem & 3) * 64;
    int n0 = (rem >> 2) * 64;
    int n4 = (tid & 15) * 4, ig = tid >> 4;   // 16 row-groups
#pragma unroll
    for (int i = ig; i < 64; i += 16) {
      float4 v = *(const float4*)(w1 + (size_t)((c0 + i) * 49 + p) * HID + n0 + n4);
      tile[i][n4] = v.x; tile[i][n4 + 1] = v.y;
      tile[i][n4 + 2] = v.z; tile[i][n4 + 3] = v.w;
    }
    __syncthreads();
    int c4 = (tid & 15) * 4;
#pragma unroll
    for (int i = ig; i < 64; i += 16) {
      __hip_bfloat16 o[4] = {__float2bfloat16(tile[c4][i]), __float2bfloat16(tile[c4 + 1][i]),
                             __float2bfloat16(tile[c4 + 2][i]), __float2bfloat16(tile[c4 + 3][i])};
      *(short4v*)(W1T + (size_t)(n0 + i) * K1P + p * 256 + c0 + c4) = *(short4v*)o;
    }
  } else if (bid < PRE_CAST0) {
    // ---------------- w2 cast: fp32 [K][N] -> bf16 [N][K], vectorized
    float (*tile)[65] = (float(*)[65])smem;
    int t = bid - PRE_CAST1;
    int c0 = (t & 15) * 64;
    int n0 = (t >> 4) * 64;
    int n4 = (tid & 15) * 4, ig = tid >> 4;
#pragma unroll
    for (int i = ig; i < 64; i += 16) {
      float4 v = *(const float4*)(w2 + (size_t)(c0 + i) * HID + n0 + n4);
      tile[i][n4] = v.x; tile[i][n4 + 1] = v.y;
      tile[i][n4 + 2] = v.z; tile[i][n4 + 3] = v.w;
    }
    __syncthreads();
    int c4 = (tid & 15) * 4;
#pragma unroll
    for (int i = ig; i < 64; i += 16) {
      __hip_bfloat16 o[4] = {__float2bfloat16(tile[c4][i]), __float2bfloat16(tile[c4 + 1][i]),
                             __float2bfloat16(tile[c4 + 2][i]), __float2bfloat16(tile[c4 + 3][i])};
      *(short4v*)(W2T + (size_t)(n0 + i) * HID + c0 + c4) = *(short4v*)o;
    }
  } else {
    // ---------------- zero K-pad cols K1..K1P of Xb / W1T
    int t = bid - PRE_CAST0;        // 0..511
    __hip_bfloat16* buf = (t >> 8) ? W1T : Xb;
    int tt = (t & 255) * 256 + tid;
    int row = tt >> 6;
    int col4 = (tt & 63) << 2;
    short4v z = {0, 0, 0, 0};
    *(short4v*)(buf + (size_t)row * K1P + K1 + col4) = z;
  }
}

// ------------------------------------------------- select + gather + encode
__global__ __launch_bounds__(256) void k_select(const float* __restrict__ prio,
    const float* __restrict__ proposals, const float* __restrict__ gt_boxes,
    const int* __restrict__ matches, const int* __restrict__ plab,
    const float* __restrict__ gt_ell,
    float* __restrict__ sel_boxes, int* __restrict__ sel_labels,
    float* __restrict__ targets) {
  int tid = threadIdx.x;
  int wave = tid >> 6, lane = tid & 63;
  int b = blockIdx.y;
  int base = b * NPROPS;
  int i = blockIdx.x * 4 + wave;
  float pi = prio[base + i];
  int rank = 0;
  for (int j = lane; j < NPROPS; j += 64) {
    float pj = prio[base + j];
    rank += (pj > pi || (pj == pi && j < i)) ? 1 : 0;
  }
#pragma unroll
  for (int off = 32; off > 0; off >>= 1) rank += __shfl_down(rank, off);
  if (lane != 0 || rank >= BPI) return;
  int slot = b * BPI + rank;
  float p0, p1, p2, p3;
  if (i < N_PROP) {
    const float* p = proposals + ((size_t)b * N_PROP + i) * 4;
    p0 = p[0]; p1 = p[1]; p2 = p[2]; p3 = p[3];
  } else {
    const float* p = gt_boxes + ((size_t)b * N_GT + (i - N_PROP)) * 4;
    p0 = p[0]; p1 = p[1]; p2 = p[2]; p3 = p[3];
  }
  sel_boxes[slot * 4 + 0] = p0;
  sel_boxes[slot * 4 + 1] = p1;
  sel_boxes[slot * 4 + 2] = p2;
  sel_boxes[slot * 4 + 3] = p3;
  int lb = plab[base + i];
  sel_labels[slot] = lb;
  int m = matches[base + i];
  const float* e = gt_ell + ((size_t)b * N_GT + m) * 5;
  float ea = e[0], eb = e[1], ex = e[2], ey = e[3], eth = e[4];
  float w = fmaxf(p2 - p0, 1.0f), h = fmaxf(p3 - p1, 1.0f);
  float cx = 0.5f * (p0 + p2), cy = 0.5f * (p1 + p3);
  float* t = targets + (size_t)slot * 6;
  t[0] = (ex - cx) / w;
  t[1] = (ey - cy) / h;
  t[2] = logf(fmaxf(2.0f * ea, 0.001f) / w);
  t[3] = logf(fmaxf(2.0f * eb, 0.001f) / h);
  t[4] = sinf(2.0f * eth);
  t[5] = cosf(2.0f * eth);
}

// ---------------- roi align (bf16 feat), b128 loads, 32 lanes x 8ch per px
// wave w serves px {2w, 2w+1} via its two 32-lane halves -> single pass,
// 16B loads/stores, ~1.75x fewer memory instructions than 8B 2-pass form.
__global__ __launch_bounds__(256) void k_roialign(const __hip_bfloat16* __restrict__ featT,
                                                  const float* __restrict__ sel_boxes,
                                                  __hip_bfloat16* __restrict__ X) {
  int n = blockIdx.x;
  int py = blockIdx.y;
  int t = threadIdx.x;
  int px = t >> 5;            // 0..7 (half-wave granularity)
  int lane32 = t & 31;
  int c = lane32 << 3;        // 8 channels / lane, 16B
  int b = n >> 9;
  const float* bx = sel_boxes + (size_t)n * 4;
  float x1 = bx[0] * 0.125f, y1 = bx[1] * 0.125f;
  float x2 = bx[2] * 0.125f, y2 = bx[3] * 0.125f;
  float bw = fmaxf(x2 - x1, 1.0f) / 7.0f;
  float bh = fmaxf(y2 - y1, 1.0f) / 7.0f;
  if (px >= 7) return;        // upper half of wave 3 idle (1/8)
  const __hip_bfloat16* base = featT + (size_t)b * HWF * C_FEAT;
  int y0A[2]; float lyA[2];
#pragma unroll
  for (int sy = 0; sy < 2; sy++) {
    float off = ((float)(py * 2 + sy) + 0.5f) * 0.5f;
    float ys = fminf(fmaxf(y1 + off * bh, 0.0f), 127.0f);
    int y0 = (int)fminf(fmaxf(floorf(ys), 0.0f), 126.0f);
    y0A[sy] = y0; lyA[sy] = ys - (float)y0;
  }
  float acc[8] = {};
#pragma unroll
  for (int sx = 0; sx < 2; sx++) {
    float off = ((float)(px * 2 + sx) + 0.5f) * 0.5f;
    float xs = fminf(fmaxf(x1 + off * bw, 0.0f), 127.0f);
    int x0 = (int)fminf(fmaxf(floorf(xs), 0.0f), 126.0f);
    float lx = xs - (float)x0;
#pragma unroll
    for (int sy = 0; sy < 2; sy++) {
      int y0 = y0A[sy]; float ly = lyA[sy];
      const __hip_bfloat16* p = base + ((size_t)(y0 * W_FEAT + x0)) * C_FEAT + c;
      bf16x8f s00 = *(const bf16x8f*)p;
      bf16x8f s01 = *(const bf16x8f*)(p + C_FEAT);
      bf16x8f s10 = *(const bf16x8f*)(p + W_FEAT * C_FEAT);
      bf16x8f s11 = *(const bf16x8f*)(p + W_FEAT * C_FEAT + C_FEAT);
      float w00 = (1.0f - ly) * (1.0f - lx), w01 = (1.0f - ly) * lx;
      float w10 = ly * (1.0f - lx), w11 = ly * lx;
#pragma unroll
      for (int q = 0; q < 8; q++) {
        float v00 = __uint_as_float(((unsigned)(unsigned short)s00[q]) << 16);
        float v01 = __uint_as_float(((unsigned)(unsigned short)s01[q]) << 16);
        float v10 = __uint_as_float(((unsigned)(unsigned short)s10[q]) << 16);
        float v11 = __uint_as_float(((unsigned)(unsigned short)s11[q]) << 16);
        acc[q] += v00 * w00 + v01 * w01 + v10 * w10 + v11 * w11;
      }
    }
  }
  __hip_bfloat16 o[8];
#pragma unroll
  for (int q = 0; q < 8; q++) o[q] = __float2bfloat16(acc[q] * 0.25f);
  *(bf16x8f*)&X[(size_t)n * K1P + (size_t)(py * 7 + px) * C_FEAT + c] = *(bf16x8f*)o;
}

// ------------------------------------------------------- global->LDS helper
__device__ __forceinline__ void gld_lds16(const __hip_bfloat16* g, __hip_bfloat16* l) {
  __builtin_amdgcn_global_load_lds(
      (const __attribute__((address_space(1))) void*)g,
      (__attribute__((address_space(3))) void*)l, 16, 0, 0);
}

// ===================== GEMM1: triple-buffered counted-vmcnt pipeline ======
// C[1024x1024] = Xb[1024xK1P] * W1T[1024xK1P]^T, split-K=8 (KC=1600).
// BM=256 BN=128 BK=64, 512 thr (8 waves of 64x64), LDS 3 x 48KB = 144KB.
//  - while computing kt (buf kt%3), S(kt+2) is issued into buf (kt+2)%3
//  - end-of-kt: s_waitcnt vmcnt(6) retires S(kt+1), leaves S(kt+2) in
//    flight; raw s_barrier (NOT __syncthreads -> would drain vmcnt(0))
//  - LDS swizzle: granule p = g ^ (row&7) via pre-swizzled GLOBAL source
//  - XCD swizzle: 8 n-siblings of each (m,kz) pair share lin%8 -> same XCD
//    L2 caches the shared A-slice once instead of 8 LLC re-fetches.
#define G1_KC   1600
#define G1_NKT  25
#define G1_ABUF 16384   // 256*64 bf16
#define G1_BUFE 24576   // A(16384) + B(8192) per buffer

__global__ __launch_bounds__(512, 1) void k_gemm1(const __hip_bfloat16* __restrict__ A,
                                                  const __hip_bfloat16* __restrict__ BT,
                                                  __hip_bfloat16* __restrict__ Pb) {
  __shared__ __align__(16) __hip_bfloat16 lds[3 * G1_BUFE];  // 144 KiB
  const int lin = blockIdx.x;
  // pair = (m,kz): constant on each XCD (bits0-2 + bits6-7); n in bits3-5
  const int pair = (lin & 7) + ((lin >> 6) << 3);   // 0..31
  const int m0 = (pair & 3) * 256;
  const int kz = pair >> 2;
  const int n0 = ((lin >> 3) & 7) * 128;
  const int kbeg = kz * G1_KC;
  const int tid = threadIdx.x;
  const int wave = tid >> 6, lane = tid & 63;
  const int wm = (wave & 3) * 64, wn = (wave >> 2) * 64;
  const int lm = lane & 15, quad = lane >> 4;

  f32x4f acc[4][4] = {};

  auto stage = [&](int kt, int sb) {
    const int kcol = kbeg + kt * 64;
    __hip_bfloat16* lb = lds + sb * G1_BUFE;
#pragma unroll
    for (int u = 0; u < 4; ++u) {              // A: 2048 granules / 512 thr
      int idx = tid + u * 512;
      int r = idx >> 3, g = (idx & 7) ^ (r & 7);
      gld_lds16(A + (size_t)(m0 + r) * K1P + kcol + g * 8, lb + idx * 8);
    }
#pragma unroll
    for (int u = 0; u < 2; ++u) {              // B: 1024 granules / 512 thr
      int idx = tid + u * 512;
      int r = idx >> 3, g = (idx & 7) ^ (r & 7);
      gld_lds16(BT + (size_t)(n0 + r) * K1P + kcol + g * 8, lb + G1_ABUF + idx * 8);
    }
  };

  stage(0, 0);
  stage(1, 1);
  asm volatile("s_waitcnt vmcnt(6)" ::: "memory");   // S(0) resident, S(1) flying
  __builtin_amdgcn_s_barrier();

  int buf = 0;
  for (int kt = 0; kt < G1_NKT; ++kt) {
    int sb = buf + 2; if (sb >= 3) sb -= 3;
    if (kt + 2 < G1_NKT) stage(kt + 2, sb);
    const __hip_bfloat16* Ab = lds + buf * G1_BUFE;
    const __hip_bfloat16* Bb = Ab + G1_ABUF;
    bf16x8f af[4][2], bf[4][2];
#pragma unroll
    for (int i = 0; i < 4; ++i)
#pragma unroll
      for (int s = 0; s < 2; ++s)
        af[i][s] = *(const bf16x8f*)(Ab + (wm + i * 16 + lm) * 64 +
                                     (((s << 2) + quad) ^ (lm & 7)) * 8);
#pragma unroll
    for (int j = 0; j < 4; ++j)
#pragma unroll
      for (int s = 0; s < 2; ++s)
        bf[j][s] = *(const bf16x8f*)(Bb + (wn + j * 16 + lm) * 64 +
                                     (((s << 2) + quad) ^ (lm & 7)) * 8);
    __builtin_amdgcn_s_setprio(1);
#pragma unroll
    for (int s = 0; s < 2; ++s)
#pragma unroll
      for (int i = 0; i < 4; ++i)
#pragma unroll
        for (int j = 0; j < 4; ++j)
          acc[i][j] = __builtin_amdgcn_mfma_f32_16x16x32_bf16(af[i][s], bf[j][s], acc[i][j], 0, 0, 0);
    __builtin_amdgcn_s_setprio(0);
    if (kt < G1_NKT - 1) {
      if (kt < G1_NKT - 2) asm volatile("s_waitcnt vmcnt(6)" ::: "memory");
      else                 asm volatile("s_waitcnt vmcnt(0)" ::: "memory");
      __builtin_amdgcn_s_barrier();
    }
    buf = (buf == 2) ? 0 : buf + 1;
  }

  // packed bf16 partials, identical layout to k_reduce16 ABI
  int tileoff = ((m0 >> 8) * 8 + (n0 >> 7)) * 32768;
  __hip_bfloat16* dst = Pb + ((size_t)kz << 20) + tileoff + wave * 4096 + lane * 4;
#pragma unroll
  for (int i = 0; i < 4; ++i)
#pragma unroll
    for (int j = 0; j < 4; ++j) {
      __hip_bfloat16 o[4] = {__float2bfloat16(acc[i][j][0]), __float2bfloat16(acc[i][j][1]),
                             __float2bfloat16(acc[i][j][2]), __float2bfloat16(acc[i][j][3])};
      *(short4v*)(dst + (i * 4 + j) * 256) = *(short4v*)o;
    }
}

// ------------------------------------------------------- bf16 MFMA GEMM (split-K)
// (retained for GEMM2; MODE2 = 128x128 tile)
template <int MODE>
__global__ __launch_bounds__(MODE == 1 ? 512 : 256)
void k_mfma_gemm(const __hip_bfloat16* __restrict__ A,
                 const __hip_bfloat16* __restrict__ BT,
                 __hip_bfloat16* __restrict__ Pb, int K, int KC) {
  const int AM  = (MODE == 1) ? 256 : 128;
  const int TPB = AM * 2;
  __shared__ __align__(16) __hip_bfloat16 As[AM * 32];
  __shared__ __align__(16) __hip_bfloat16 Bs[128 * 32];
  int lin = blockIdx.x;
  int n0, m0, kz;
  if (MODE == 1) {
    int c = lin & 7, h = lin >> 8, qq = (lin >> 3) & 31;
    kz = c + (h << 3);
    n0 = (qq & 7) * 128;
    m0 = (qq >> 3) * 256;
  } else {
    kz = lin & 7;
    int qq = lin >> 3;
    n0 = (qq & 7) * 128;
    m0 = (qq >> 3) * 128;
  }
  int tid = threadIdx.x;
  int kbeg = kz * KC;
  int srow = tid >> 2;
  int scs  = tid & 3;
  int sg   = scs ^ (srow & 3);
  int scol = sg << 3;
  int wave = tid >> 6, lane = tid & 63;
  const int WMW = AM / 64;
  int wm = (wave % WMW) * 64, wn = (wave / WMW) * 64;
  int lm = lane & 15, quad = lane >> 4;
  int fco = ((quad ^ (lm & 3)) << 3);
  f32x4f acc[4][4] = {};
  for (int k0 = kbeg; k0 < kbeg + KC; k0 += 32) {
    __syncthreads();
#pragma unroll
    for (int r0 = 0; r0 < AM; r0 += TPB / 4)
      gld_lds16(A + (size_t)(m0 + r0 + srow) * K + k0 + scol, &As[(r0 + srow) * 32 + scs * 8]);
#pragma unroll
    for (int r0 = 0; r0 < 128; r0 += TPB / 4)
      gld_lds16(BT + (size_t)(n0 + r0 + srow) * K + k0 + scol, &Bs[(r0 + srow) * 32 + scs * 8]);
    __syncthreads();
    bf16x8f af[4], bf[4];
#pragma unroll
    for (int i = 0; i < 4; i++)
      af[i] = *(const bf16x8f*)&As[(wm + i * 16 + lm) * 32 + fco];
#pragma unroll
    for (int j = 0; j < 4; j++)
      bf[j] = *(const bf16x8f*)&Bs[(wn + j * 16 + lm) * 32 + fco];
#pragma unroll
    for (int i = 0; i < 4; i++)
#pragma unroll
      for (int j = 0; j < 4; j++)
        acc[i][j] = __builtin_amdgcn_mfma_f32_16x16x32_bf16(af[i], bf[j], acc[i][j], 0, 0, 0);
  }
  int tileoff = (MODE == 1) ? (((m0 >> 8) * 8 + (n0 >> 7)) * 32768)
                            : (((m0 >> 7) * 8 + (n0 >> 7)) * 16384);
  __hip_bfloat16* dst = Pb + ((size_t)kz << 20) + tileoff + wave * 4096 + lane * 4;
#pragma unroll
  for (int i = 0; i < 4; i++)
#pragma unroll
    for (int j = 0; j < 4; j++) {
      __hip_bfloat16 o[4] = {__float2bfloat16(acc[i][j][0]), __float2bfloat16(acc[i][j][1]),
                             __float2bfloat16(acc[i][j][2]), __float2bfloat16(acc[i][j][3])};
      *(short4v*)(dst + (i * 4 + j) * 256) = *(short4v*)o;
    }
}

// ---------------- reduce GEMM1 packed partials + bias + relu -> H1b (bf16)
__global__ __launch_bounds__(256) void k_reduce16(const __hip_bfloat16* __restrict__ Pb,
                                                  const float* __restrict__ bias,
                                                  __hip_bfloat16* __restrict__ O) {
  int m4 = blockIdx.x >> 2;
  int n  = (blockIdx.x & 3) * 256 + threadIdx.x;
  int m0i = m4 >> 6, wavem = (m4 >> 4) & 3, i = (m4 >> 2) & 3, quad = m4 & 3;
  int n0i = n >> 7, wn = (n >> 6) & 1, j = (n >> 4) & 3, lm = n & 15;
  int wave = wavem + wn * 4;
  int elem = (m0i * 8 + n0i) * 32768 + wave * 4096 + (i * 4 + j) * 256 + (quad * 16 + lm) * 4;
  float s0 = 0.0f, s1 = 0.0f, s2 = 0.0f, s3 = 0.0f;
#pragma unroll
  for (int z = 0; z < SPLITK1; z++) {
    short4v v = *(const short4v*)(Pb + ((size_t)z << 20) + elem);
    s0 += __uint_as_float(((unsigned)(unsigned short)v[0]) << 16);
    s1 += __uint_as_float(((unsigned)(unsigned short)v[1]) << 16);
    s2 += __uint_as_float(((unsigned)(unsigned short)v[2]) << 16);
    s3 += __uint_as_float(((unsigned)(unsigned short)v[3]) << 16);
  }
  float bv = bias[n];
  int m = m4 * 4;
  O[(size_t)(m + 0) * HID + n] = __float2bfloat16(fmaxf(s0 + bv, 0.0f));
  O[(size_t)(m + 1) * HID + n] = __float2bfloat16(fmaxf(s1 + bv, 0.0f));
  O[(size_t)(m + 2) * HID + n] = __float2bfloat16(fmaxf(s2 + bv, 0.0f));
  O[(size_t)(m + 3) * HID + n] = __float2bfloat16(fmaxf(s3 + bv, 0.0f));
}

// -------- reduce GEMM2 partials + bias + relu + head + FUSED LOSS.
// Last block (device-scope atomic, mod-1024 so workspace poison is harmless)
// computes both losses directly -> removes the separate 1-block k_loss launch.
__global__ __launch_bounds__(256) void k_reduce_head(const __hip_bfloat16* __restrict__ Pb,
                                                     const float* __restrict__ bias,
                                                     const float* __restrict__ wc,
                                                     const float* __restrict__ bc,
                                                     const float* __restrict__ wr,
                                                     const float* __restrict__ br,
                                                     float* __restrict__ Y,
                                                     const int* __restrict__ sel_labels,
                                                     const float* __restrict__ T,
                                                     float* __restrict__ out,
                                                     int* __restrict__ loss_cnt) {
  __shared__ float part[4][NHEAD];
  __shared__ int lastf;
  __shared__ float rcs[4], rrs[4];
  int m = blockIdx.x, tid = threadIdx.x;
  int m0i = m >> 7, wavem = (m >> 6) & 1, fi = (m >> 4) & 3, quad = (m >> 2) & 3, r = m & 3;
  float a[NHEAD];
#pragma unroll
  for (int j = 0; j < NHEAD; j++) a[j] = 0.0f;
#pragma unroll
  for (int nn = 0; nn < 4; nn++) {
    int n = nn * 256 + tid;
    int n0i = n >> 7, wn = (n >> 6) & 1, fj = (n >> 4) & 3, lm = n & 15;
    int wave = wavem + wn * 2;
    int elem = (m0i * 8 + n0i) * 16384 + wave * 4096 + (fi * 4 + fj) * 256
             + (quad * 16 + lm) * 4 + r;
    float s = 0.0f;
#pragma unroll
    for (int z = 0; z < SPLITK2; z++)
      s += __uint_as_float(((unsigned)*(const unsigned short*)(Pb + ((size_t)z << 20) + elem)) << 16);
    float hv = fmaxf(s + bias[n], 0.0f);
    float2 wcv = *(const float2*)(wc + n * 2);
    float4 w0 = *(const float4*)(wr + n * 12);
    float4 w1 = *(const float4*)(wr + n * 12 + 4);
    float4 w2 = *(const float4*)(wr + n * 12 + 8);
    a[0] += hv * wcv.x;  a[1] += hv * wcv.y;
    a[2] += hv * w0.x;   a[3] += hv * w0.y;  a[4] += hv * w0.z;  a[5] += hv * w0.w;
    a[6] += hv * w1.x;   a[7] += hv * w1.y;  a[8] += hv * w1.z;  a[9] += hv * w1.w;
    a[10] += hv * w2.x;  a[11] += hv * w2.y; a[12] += hv * w2.z; a[13] += hv * w2.w;
  }
#pragma unroll
  for (int j = 0; j < NHEAD; j++)
#pragma unroll
    for (int off = 32; off > 0; off >>= 1) a[j] += __shfl_down(a[j], off);
  int wave = tid >> 6, lane = tid & 63;
  if (lane == 0)
#pragma unroll
    for (int j = 0; j < NHEAD; j++) part[wave][j] = a[j];
  __syncthreads();
  if (tid < NHEAD) {
    float v = part[0][tid] + part[1][tid] + part[2][tid] + part[3][tid];
    Y[(size_t)m * NHEAD + tid] = v + ((tid < 2) ? bc[tid] : br[tid - 2]);
  }
  // ---------------- last-block loss
  __syncthreads();
  if (tid == 0) {
    __threadfence();                       // release our Y row
    int old = atomicAdd(loss_cnt, 1);      // device-scope
    lastf = ((old & 1023) == 1023) ? 1 : 0;
  }
  __syncthreads();
  if (!lastf) return;
  __threadfence();                         // acquire all Y rows
  float ce_s = 0.0f, rg_s = 0.0f;
#pragma unroll
  for (int k2 = 0; k2 < 4; k2++) {
    int s = tid + k2 * 256;
    float l0 = Y[(size_t)s * NHEAD + 0], l1 = Y[(size_t)s * NHEAD + 1];
    int lb = sel_labels[s];
    float mx = fmaxf(l0, l1);
    float lse = mx + logf(expf(l0 - mx) + expf(l1 - mx));
    ce_s += lse - (lb ? l1 : l0);
    if (lb > 0) {
      const float beta = 1.0f / 9.0f;
      const float* pr = Y + (size_t)s * NHEAD + 2 + lb * 6;
      const float* tt = T + (size_t)s * 6;
#pragma unroll
      for (int j = 0; j < 6; j++) {
        float d = fabsf(pr[j] - tt[j]);
        rg_s += (d < beta) ? (0.5f * d * d / beta) : (d - 0.5f * beta);
      }
    }
  }
#pragma unroll
  for (int off = 32; off > 0; off >>= 1) {
    ce_s += __shfl_down(ce_s, off);
    rg_s += __shfl_down(rg_s, off);
  }
  if (lane == 0) { rcs[wave] = ce_s; rrs[wave] = rg_s; }
  __syncthreads();
  if (tid == 0) {
    out[0] = (rcs[0] + rcs[1] + rcs[2] + rcs[3]) * (1.0f / 1024.0f);
    out[1] = (rrs[0] + rrs[1] + rrs[2] + rrs[3]) * (1.0f / 1024.0f);
  }
}

// ------------------------------------------------------------------ launch
extern "C" void kernel_launch(void* const* d_in, const int* in_sizes, int n_in,
                              void* d_out, int out_size, void* d_ws, size_t ws_size,
                              hipStream_t stream) {
  const float* features  = (const float*)d_in[0];
  const float* proposals = (const float*)d_in[1];
  const float* gt_boxes  = (const float*)d_in[2];
  const int*   gt_labels = (const int*)d_in[3];
  const float* gt_ell    = (const float*)d_in[4];
  const float* w1 = (const float*)d_in[5];
  const float* b1 = (const float*)d_in[6];
  const float* w2 = (const float*)d_in[7];
  const float* b2 = (const float*)d_in[8];
  const float* wc = (const float*)d_in[9];
  const float* bc = (const float*)d_in[10];
  const float* wr = (const float*)d_in[11];
  const float* br = (const float*)d_in[12];
  float* out = (float*)d_out;

  char* ws = (char*)d_ws;
  size_t off = 0;
  auto take = [&](size_t bytes) -> void* {
    void* p = ws + off;
    off = (off + bytes + 255) & ~(size_t)255;
    return p;
  };
  // Pb reservation kept at 16 x 2 MiB (layout stability); 8 slabs used now.
  // featT (16.7 MB) aliases Pb pre-GEMM.
  __hip_bfloat16* Pb = (__hip_bfloat16*)take((size_t)16 * (1 << 20) * 2);      // 33.5 MB
  __hip_bfloat16* featT = Pb;                                                  // alias
  __hip_bfloat16* Xb  = (__hip_bfloat16*)take((size_t)NSEL * K1P * 2);         // 26.2 MB
  float* Y = (float*)Xb;                                                       // alias (post-GEMM1)
  __hip_bfloat16* W1T = (__hip_bfloat16*)take((size_t)HID * K1P * 2);          // 26.2 MB
  __hip_bfloat16* W2T = (__hip_bfloat16*)take((size_t)HID * HID * 2);          // 2.1 MB
  __hip_bfloat16* H1b = (__hip_bfloat16*)take((size_t)NSEL * HID * 2);         // 2.1 MB
  int*   matches   = (int*)take((size_t)B_IMG * NPROPS * 4);
  int*   plab      = (int*)take((size_t)B_IMG * NPROPS * 4);
  float* prio      = (float*)take((size_t)B_IMG * NPROPS * 4);
  float* sel_boxes = (float*)take((size_t)NSEL * 4 * 4);
  int*   sel_lab   = (int*)take((size_t)NSEL * 4);
  float* targets   = (float*)take((size_t)NSEL * 6 * 4);
  int*   loss_cnt  = (int*)take(256);

  k_pre<<<PRE_TOTAL, 256, 0, stream>>>(proposals, gt_boxes, gt_labels, features,
                                       w1, w2, prio, plab, matches,
                                       featT, W1T, W2T, Xb);
  k_select<<<dim3(NPROPS / 4, B_IMG), 256, 0, stream>>>(prio, proposals, gt_boxes,
                                                        matches, plab, gt_ell,
                                                        sel_boxes, sel_lab, targets);
  k_roialign<<<dim3(NSEL, POOL), 256, 0, stream>>>(featT, sel_boxes, Xb);

  // GEMM1: 256x128 tile, BK=64, triple-buffered counted-vmcnt, split-K=8
  k_gemm1<<<256, 512, 0, stream>>>(Xb, W1T, Pb);
  k_reduce16<<<1024, 256, 0, stream>>>(Pb, b1, H1b);
  // GEMM2: 128x128 tile, split-K=8 (KC=128), 512 blocks -> fused reduce+relu+head+loss
  k_mfma_gemm<2><<<512, 256, 0, stream>>>(H1b, W2T, Pb, HID, HID / SPLITK2);
  k_reduce_head<<<1024, 256, 0, stream>>>(Pb, b2, wc, bc, wr, br, Y,
                                          sel_lab, targets, out, loss_cnt);
}

// Round 3
// 243.619 us; speedup vs baseline: 1.0575x; 1.0575x over previous
//
#include <hip/hip_runtime.h>
#include <hip/hip_bf16.h>
#include <math.h>

#define B_IMG   2
#define N_PROP  2000
#define N_GT    16
#define NPROPS  2016        // N_PROP + N_GT
#define C_FEAT  256
#define H_FEAT  128
#define W_FEAT  128
#define HWF     (H_FEAT*W_FEAT)
#define POOL    7
#define BPI     512
#define NPOSMAX 128
#define NSEL    (B_IMG*BPI)     // 1024
#define K1      (C_FEAT*POOL*POOL)  // 12544
#define K1P     12800           // K1 padded to 16*800
#define HID     1024
#define NHEAD   14
#define SPLITK1 8               // KC = 1600 (pipelined GEMM1)

typedef short bf16x8f __attribute__((ext_vector_type(8)));
typedef float f32x4f  __attribute__((ext_vector_type(4)));
typedef short short4v __attribute__((ext_vector_type(4)));

// ---------------------------------------------------------------- threefry
__device__ __forceinline__ void threefry2x32(unsigned k0, unsigned k1,
                                             unsigned& x0, unsigned& x1) {
  unsigned ks[3] = {k0, k1, k0 ^ k1 ^ 0x1BD11BDAu};
  const int R0[4] = {13, 15, 26, 6};
  const int R1[4] = {17, 29, 16, 24};
  x0 += ks[0]; x1 += ks[1];
#pragma unroll
  for (int g = 0; g < 5; g++) {
    const int* rot = (g & 1) ? R1 : R0;
#pragma unroll
    for (int r = 0; r < 4; r++) {
      x0 += x1;
      x1 = (x1 << rot[r]) | (x1 >> (32 - rot[r]));
      x1 ^= x0;
    }
    x0 += ks[(g + 1) % 3];
    x1 += ks[(g + 2) % 3] + (unsigned)(g + 1);
  }
}

// ---------------- mega-prologue: sample(2) | transpose(2048) | castT1(3136)
//                  | castT0(256) | pad(512)  — blockIdx-range dispatch
#define PRE_SAMPLE   2
#define PRE_TRANS    (PRE_SAMPLE + 2048)
#define PRE_CAST1    (PRE_TRANS + 3136)
#define PRE_CAST0    (PRE_CAST1 + 256)
#define PRE_TOTAL    (PRE_CAST0 + 512)

__global__ __launch_bounds__(256) void k_pre(const float* __restrict__ proposals,
                                             const float* __restrict__ gt_boxes,
                                             const int* __restrict__ gt_labels,
                                             const float* __restrict__ features,
                                             const float* __restrict__ w1,
                                             const float* __restrict__ w2,
                                             float* __restrict__ prio,
                                             int* __restrict__ plab,
                                             int* __restrict__ matches,
                                             __hip_bfloat16* __restrict__ featT,
                                             __hip_bfloat16* __restrict__ W1T,
                                             __hip_bfloat16* __restrict__ W2T,
                                             __hip_bfloat16* __restrict__ Xb) {
  __shared__ __align__(16) char smem[20800];
  int bid = blockIdx.x;
  int tid = threadIdx.x;
  if (bid < PRE_SAMPLE) {
    // ---------------- sample: rand + IoU match + positive-rank priorities
    float* rs    = (float*)smem;              // 2016
    float* pos_r = (float*)(smem + 8064);     // 2016
    short* pos_i = (short*)(smem + 16128);    // 2016
    float* gtb   = (float*)(smem + 20160);    // 64
    int*   gtl   = (int*)(smem + 20416);      // 16
    int*   cnt   = (int*)(smem + 20480);
    int b = bid;
    int base = b * NPROPS;
    if (tid == 0) *cnt = 0;
    if (tid < N_GT * 4) gtb[tid] = gt_boxes[b * N_GT * 4 + tid];
    if (tid < N_GT) gtl[tid] = gt_labels[b * N_GT + tid];
    __syncthreads();
    for (int i = tid; i < NPROPS; i += 256) {
      unsigned x0 = 0u, x1 = (unsigned)(base + i);
      threefry2x32(0u, 42u, x0, x1);
      unsigned bits = x0 ^ x1;
      float r = __uint_as_float((bits >> 9) | 0x3F800000u) - 1.0f;
      rs[i] = r;
      float p0, p1, p2, p3;
      if (i < N_PROP) {
        const float4 v = *(const float4*)(proposals + ((size_t)b * N_PROP + i) * 4);
        p0 = v.x; p1 = v.y; p2 = v.z; p3 = v.w;
      } else {
        const float* g = &gtb[(i - N_PROP) * 4];
        p0 = g[0]; p1 = g[1]; p2 = g[2]; p3 = g[3];
      }
      float a2 = (p2 - p0) * (p3 - p1);
      float best = -1.0f; int bg = 0;
#pragma unroll
      for (int g = 0; g < N_GT; g++) {
        float g0 = gtb[g*4], g1 = gtb[g*4+1], g2 = gtb[g*4+2], g3 = gtb[g*4+3];
        float a1 = (g2 - g0) * (g3 - g1);
        float wx = fmaxf(fminf(g2, p2) - fmaxf(g0, p0), 0.0f);
        float wy = fmaxf(fminf(g3, p3) - fmaxf(g1, p1), 0.0f);
        float inter = wx * wy;
        float iou = inter / (a1 + a2 - inter);
        if (iou > best) { best = iou; bg = g; }
      }
      matches[base + i] = bg;
      int lab = (best < 0.5f) ? 0 : gtl[bg];
      plab[base + i] = lab;
      if (lab > 0) {
        int s = atomicAdd(cnt, 1);
        pos_i[s] = (short)i; pos_r[s] = r;
      }
    }
    __syncthreads();
    int P = *cnt;
    for (int s = tid; s < P; s += 256) {
      int i = pos_i[s]; float ri = pos_r[s];
      int ch = 0;
      for (int j = 0; j < P; j++) {
        float rj = pos_r[j]; int ij = pos_i[j];
        ch += (rj > ri || (rj == ri && ij < i)) ? 1 : 0;
      }
      rs[i] = (ch < NPOSMAX) ? (ri + 2.0f) : -1000000000.0f;
    }
    __syncthreads();
    for (int i = tid; i < NPROPS; i += 256) prio[base + i] = rs[i];
  } else if (bid < PRE_TRANS) {
    // ---------------- NCHW -> NHWC bf16, 64x64 tiles
    float (*tile)[65] = (float(*)[65])smem;
    int t = bid - PRE_SAMPLE;
    int b = t >> 10;
    int rem = t & 1023;
    int c0 = (rem >> 8) * 64;
    int s0 = (rem & 255) * 64;
    const float* src = features + (size_t)b * C_FEAT * HWF;
    __hip_bfloat16* dst = featT + (size_t)b * HWF * C_FEAT;
    int hw4 = (tid & 15) * 4, cr = tid >> 4;
#pragma unroll
    for (int p = 0; p < 4; p++) {
      int c = cr + p * 16;
      float4 v = *(const float4*)(src + (size_t)(c0 + c) * HWF + s0 + hw4);
      tile[hw4 + 0][c] = v.x; tile[hw4 + 1][c] = v.y;
      tile[hw4 + 2][c] = v.z; tile[hw4 + 3][c] = v.w;
    }
    __syncthreads();
    int c4 = (tid & 15) * 4, hr = tid >> 4;
#pragma unroll
    for (int p = 0; p < 4; p++) {
      int hw = hr + p * 16;
      __hip_bfloat16 o[4] = {__float2bfloat16(tile[hw][c4]), __float2bfloat16(tile[hw][c4+1]),
                             __float2bfloat16(tile[hw][c4+2]), __float2bfloat16(tile[hw][c4+3])};
      *(short4v*)(dst + (size_t)(s0 + hw) * C_FEAT + c0 + c4) = *(short4v*)o;
    }
  } else if (bid < PRE_CAST1) {
    // ---------------- w1 cast: fp32 [c*49+p][N] -> bf16 [N][p*256+c]
    float (*tile)[65] = (float(*)[65])smem;
    int t = bid - PRE_TRANS;
    int p = t >> 6;
    int rem = t & 63;
    int c0 = (rem & 3) * 64;
    int n0 = (rem >> 2) * 64;
    int n4 = (tid & 15) * 4, ig = tid >> 4;   // 16 row-groups
#pragma unroll
    for (int i = ig; i < 64; i += 16) {
      float4 v = *(const float4*)(w1 + (size_t)((c0 + i) * 49 + p) * HID + n0 + n4);
      tile[i][n4] = v.x; tile[i][n4 + 1] = v.y;
      tile[i][n4 + 2] = v.z; tile[i][n4 + 3] = v.w;
    }
    __syncthreads();
    int c4 = (tid & 15) * 4;
#pragma unroll
    for (int i = ig; i < 64; i += 16) {
      __hip_bfloat16 o[4] = {__float2bfloat16(tile[c4][i]), __float2bfloat16(tile[c4 + 1][i]),
                             __float2bfloat16(tile[c4 + 2][i]), __float2bfloat16(tile[c4 + 3][i])};
      *(short4v*)(W1T + (size_t)(n0 + i) * K1P + p * 256 + c0 + c4) = *(short4v*)o;
    }
  } else if (bid < PRE_CAST0) {
    // ---------------- w2 cast: fp32 [K][N] -> bf16 [N][K], vectorized
    float (*tile)[65] = (float(*)[65])smem;
    int t = bid - PRE_CAST1;
    int c0 = (t & 15) * 64;
    int n0 = (t >> 4) * 64;
    int n4 = (tid & 15) * 4, ig = tid >> 4;
#pragma unroll
    for (int i = ig; i < 64; i += 16) {
      float4 v = *(const float4*)(w2 + (size_t)(c0 + i) * HID + n0 + n4);
      tile[i][n4] = v.x; tile[i][n4 + 1] = v.y;
      tile[i][n4 + 2] = v.z; tile[i][n4 + 3] = v.w;
    }
    __syncthreads();
    int c4 = (tid & 15) * 4;
#pragma unroll
    for (int i = ig; i < 64; i += 16) {
      __hip_bfloat16 o[4] = {__float2bfloat16(tile[c4][i]), __float2bfloat16(tile[c4 + 1][i]),
                             __float2bfloat16(tile[c4 + 2][i]), __float2bfloat16(tile[c4 + 3][i])};
      *(short4v*)(W2T + (size_t)(n0 + i) * HID + c0 + c4) = *(short4v*)o;
    }
  } else {
    // ---------------- zero K-pad cols K1..K1P of Xb / W1T
    int t = bid - PRE_CAST0;        // 0..511
    __hip_bfloat16* buf = (t >> 8) ? W1T : Xb;
    int tt = (t & 255) * 256 + tid;
    int row = tt >> 6;
    int col4 = (tt & 63) << 2;
    short4v z = {0, 0, 0, 0};
    *(short4v*)(buf + (size_t)row * K1P + K1 + col4) = z;
  }
}

// ------------------------------------------------- select + gather + encode
__global__ __launch_bounds__(256) void k_select(const float* __restrict__ prio,
    const float* __restrict__ proposals, const float* __restrict__ gt_boxes,
    const int* __restrict__ matches, const int* __restrict__ plab,
    const float* __restrict__ gt_ell,
    float* __restrict__ sel_boxes, int* __restrict__ sel_labels,
    float* __restrict__ targets) {
  int tid = threadIdx.x;
  int wave = tid >> 6, lane = tid & 63;
  int b = blockIdx.y;
  int base = b * NPROPS;
  int i = blockIdx.x * 4 + wave;
  float pi = prio[base + i];
  int rank = 0;
  for (int j = lane; j < NPROPS; j += 64) {
    float pj = prio[base + j];
    rank += (pj > pi || (pj == pi && j < i)) ? 1 : 0;
  }
#pragma unroll
  for (int off = 32; off > 0; off >>= 1) rank += __shfl_down(rank, off);
  if (lane != 0 || rank >= BPI) return;
  int slot = b * BPI + rank;
  float p0, p1, p2, p3;
  if (i < N_PROP) {
    const float* p = proposals + ((size_t)b * N_PROP + i) * 4;
    p0 = p[0]; p1 = p[1]; p2 = p[2]; p3 = p[3];
  } else {
    const float* p = gt_boxes + ((size_t)b * N_GT + (i - N_PROP)) * 4;
    p0 = p[0]; p1 = p[1]; p2 = p[2]; p3 = p[3];
  }
  sel_boxes[slot * 4 + 0] = p0;
  sel_boxes[slot * 4 + 1] = p1;
  sel_boxes[slot * 4 + 2] = p2;
  sel_boxes[slot * 4 + 3] = p3;
  int lb = plab[base + i];
  sel_labels[slot] = lb;
  int m = matches[base + i];
  const float* e = gt_ell + ((size_t)b * N_GT + m) * 5;
  float ea = e[0], eb = e[1], ex = e[2], ey = e[3], eth = e[4];
  float w = fmaxf(p2 - p0, 1.0f), h = fmaxf(p3 - p1, 1.0f);
  float cx = 0.5f * (p0 + p2), cy = 0.5f * (p1 + p3);
  float* t = targets + (size_t)slot * 6;
  t[0] = (ex - cx) / w;
  t[1] = (ey - cy) / h;
  t[2] = logf(fmaxf(2.0f * ea, 0.001f) / w);
  t[3] = logf(fmaxf(2.0f * eb, 0.001f) / h);
  t[4] = sinf(2.0f * eth);
  t[5] = cosf(2.0f * eth);
}

// ---------------- roi align (bf16 feat), b128 loads, 32 lanes x 8ch per px
__global__ __launch_bounds__(256) void k_roialign(const __hip_bfloat16* __restrict__ featT,
                                                  const float* __restrict__ sel_boxes,
                                                  __hip_bfloat16* __restrict__ X) {
  int n = blockIdx.x;
  int py = blockIdx.y;
  int t = threadIdx.x;
  int px = t >> 5;            // 0..7 (half-wave granularity)
  int lane32 = t & 31;
  int c = lane32 << 3;        // 8 channels / lane, 16B
  int b = n >> 9;
  const float* bx = sel_boxes + (size_t)n * 4;
  float x1 = bx[0] * 0.125f, y1 = bx[1] * 0.125f;
  float x2 = bx[2] * 0.125f, y2 = bx[3] * 0.125f;
  float bw = fmaxf(x2 - x1, 1.0f) / 7.0f;
  float bh = fmaxf(y2 - y1, 1.0f) / 7.0f;
  if (px >= 7) return;        // upper half of wave 3 idle (1/8)
  const __hip_bfloat16* base = featT + (size_t)b * HWF * C_FEAT;
  int y0A[2]; float lyA[2];
#pragma unroll
  for (int sy = 0; sy < 2; sy++) {
    float off = ((float)(py * 2 + sy) + 0.5f) * 0.5f;
    float ys = fminf(fmaxf(y1 + off * bh, 0.0f), 127.0f);
    int y0 = (int)fminf(fmaxf(floorf(ys), 0.0f), 126.0f);
    y0A[sy] = y0; lyA[sy] = ys - (float)y0;
  }
  float acc[8] = {};
#pragma unroll
  for (int sx = 0; sx < 2; sx++) {
    float off = ((float)(px * 2 + sx) + 0.5f) * 0.5f;
    float xs = fminf(fmaxf(x1 + off * bw, 0.0f), 127.0f);
    int x0 = (int)fminf(fmaxf(floorf(xs), 0.0f), 126.0f);
    float lx = xs - (float)x0;
#pragma unroll
    for (int sy = 0; sy < 2; sy++) {
      int y0 = y0A[sy]; float ly = lyA[sy];
      const __hip_bfloat16* p = base + ((size_t)(y0 * W_FEAT + x0)) * C_FEAT + c;
      bf16x8f s00 = *(const bf16x8f*)p;
      bf16x8f s01 = *(const bf16x8f*)(p + C_FEAT);
      bf16x8f s10 = *(const bf16x8f*)(p + W_FEAT * C_FEAT);
      bf16x8f s11 = *(const bf16x8f*)(p + W_FEAT * C_FEAT + C_FEAT);
      float w00 = (1.0f - ly) * (1.0f - lx), w01 = (1.0f - ly) * lx;
      float w10 = ly * (1.0f - lx), w11 = ly * lx;
#pragma unroll
      for (int q = 0; q < 8; q++) {
        float v00 = __uint_as_float(((unsigned)(unsigned short)s00[q]) << 16);
        float v01 = __uint_as_float(((unsigned)(unsigned short)s01[q]) << 16);
        float v10 = __uint_as_float(((unsigned)(unsigned short)s10[q]) << 16);
        float v11 = __uint_as_float(((unsigned)(unsigned short)s11[q]) << 16);
        acc[q] += v00 * w00 + v01 * w01 + v10 * w10 + v11 * w11;
      }
    }
  }
  __hip_bfloat16 o[8];
#pragma unroll
  for (int q = 0; q < 8; q++) o[q] = __float2bfloat16(acc[q] * 0.25f);
  *(bf16x8f*)&X[(size_t)n * K1P + (size_t)(py * 7 + px) * C_FEAT + c] = *(bf16x8f*)o;
}

// ------------------------------------------------------- global->LDS helper
__device__ __forceinline__ void gld_lds16(const __hip_bfloat16* g, __hip_bfloat16* l) {
  __builtin_amdgcn_global_load_lds(
      (const __attribute__((address_space(1))) void*)g,
      (__attribute__((address_space(3))) void*)l, 16, 0, 0);
}

// ===================== GEMM1: triple-buffered counted-vmcnt pipeline ======
// C[1024x1024] = Xb[1024xK1P] * W1T[1024xK1P]^T, split-K=8 (KC=1600).
// BM=256 BN=128 BK=64, 512 thr (8 waves of 64x64), LDS 3 x 48KB = 144KB.
#define G1_KC   1600
#define G1_NKT  25
#define G1_ABUF 16384   // 256*64 bf16
#define G1_BUFE 24576   // A(16384) + B(8192) per buffer

__global__ __launch_bounds__(512, 1) void k_gemm1(const __hip_bfloat16* __restrict__ A,
                                                  const __hip_bfloat16* __restrict__ BT,
                                                  __hip_bfloat16* __restrict__ Pb) {
  __shared__ __align__(16) __hip_bfloat16 lds[3 * G1_BUFE];  // 144 KiB
  const int lin = blockIdx.x;
  // pair = (m,kz): constant on each XCD (bits0-2 + bits6-7); n in bits3-5
  const int pair = (lin & 7) + ((lin >> 6) << 3);   // 0..31
  const int m0 = (pair & 3) * 256;
  const int kz = pair >> 2;
  const int n0 = ((lin >> 3) & 7) * 128;
  const int kbeg = kz * G1_KC;
  const int tid = threadIdx.x;
  const int wave = tid >> 6, lane = tid & 63;
  const int wm = (wave & 3) * 64, wn = (wave >> 2) * 64;
  const int lm = lane & 15, quad = lane >> 4;

  f32x4f acc[4][4] = {};

  auto stage = [&](int kt, int sb) {
    const int kcol = kbeg + kt * 64;
    __hip_bfloat16* lb = lds + sb * G1_BUFE;
#pragma unroll
    for (int u = 0; u < 4; ++u) {              // A: 2048 granules / 512 thr
      int idx = tid + u * 512;
      int r = idx >> 3, g = (idx & 7) ^ (r & 7);
      gld_lds16(A + (size_t)(m0 + r) * K1P + kcol + g * 8, lb + idx * 8);
    }
#pragma unroll
    for (int u = 0; u < 2; ++u) {              // B: 1024 granules / 512 thr
      int idx = tid + u * 512;
      int r = idx >> 3, g = (idx & 7) ^ (r & 7);
      gld_lds16(BT + (size_t)(n0 + r) * K1P + kcol + g * 8, lb + G1_ABUF + idx * 8);
    }
  };

  stage(0, 0);
  stage(1, 1);
  asm volatile("s_waitcnt vmcnt(6)" ::: "memory");   // S(0) resident, S(1) flying
  __builtin_amdgcn_s_barrier();

  int buf = 0;
  for (int kt = 0; kt < G1_NKT; ++kt) {
    int sb = buf + 2; if (sb >= 3) sb -= 3;
    if (kt + 2 < G1_NKT) stage(kt + 2, sb);
    const __hip_bfloat16* Ab = lds + buf * G1_BUFE;
    const __hip_bfloat16* Bb = Ab + G1_ABUF;
    bf16x8f af[4][2], bf[4][2];
#pragma unroll
    for (int i = 0; i < 4; ++i)
#pragma unroll
      for (int s = 0; s < 2; ++s)
        af[i][s] = *(const bf16x8f*)(Ab + (wm + i * 16 + lm) * 64 +
                                     (((s << 2) + quad) ^ (lm & 7)) * 8);
#pragma unroll
    for (int j = 0; j < 4; ++j)
#pragma unroll
      for (int s = 0; s < 2; ++s)
        bf[j][s] = *(const bf16x8f*)(Bb + (wn + j * 16 + lm) * 64 +
                                     (((s << 2) + quad) ^ (lm & 7)) * 8);
    __builtin_amdgcn_s_setprio(1);
#pragma unroll
    for (int s = 0; s < 2; ++s)
#pragma unroll
      for (int i = 0; i < 4; ++i)
#pragma unroll
        for (int j = 0; j < 4; ++j)
          acc[i][j] = __builtin_amdgcn_mfma_f32_16x16x32_bf16(af[i][s], bf[j][s], acc[i][j], 0, 0, 0);
    __builtin_amdgcn_s_setprio(0);
    if (kt < G1_NKT - 1) {
      if (kt < G1_NKT - 2) asm volatile("s_waitcnt vmcnt(6)" ::: "memory");
      else                 asm volatile("s_waitcnt vmcnt(0)" ::: "memory");
      __builtin_amdgcn_s_barrier();
    }
    buf = (buf == 2) ? 0 : buf + 1;
  }

  // packed bf16 partials, identical layout to k_reduce16 ABI
  int tileoff = ((m0 >> 8) * 8 + (n0 >> 7)) * 32768;
  __hip_bfloat16* dst = Pb + ((size_t)kz << 20) + tileoff + wave * 4096 + lane * 4;
#pragma unroll
  for (int i = 0; i < 4; ++i)
#pragma unroll
    for (int j = 0; j < 4; ++j) {
      __hip_bfloat16 o[4] = {__float2bfloat16(acc[i][j][0]), __float2bfloat16(acc[i][j][1]),
                             __float2bfloat16(acc[i][j][2]), __float2bfloat16(acc[i][j][3])};
      *(short4v*)(dst + (i * 4 + j) * 256) = *(short4v*)o;
    }
}

// ---------------- reduce GEMM1 packed partials + bias + relu -> H1b (bf16)
__global__ __launch_bounds__(256) void k_reduce16(const __hip_bfloat16* __restrict__ Pb,
                                                  const float* __restrict__ bias,
                                                  __hip_bfloat16* __restrict__ O) {
  int m4 = blockIdx.x >> 2;
  int n  = (blockIdx.x & 3) * 256 + threadIdx.x;
  int m0i = m4 >> 6, wavem = (m4 >> 4) & 3, i = (m4 >> 2) & 3, quad = m4 & 3;
  int n0i = n >> 7, wn = (n >> 6) & 1, j = (n >> 4) & 3, lm = n & 15;
  int wave = wavem + wn * 4;
  int elem = (m0i * 8 + n0i) * 32768 + wave * 4096 + (i * 4 + j) * 256 + (quad * 16 + lm) * 4;
  float s0 = 0.0f, s1 = 0.0f, s2 = 0.0f, s3 = 0.0f;
#pragma unroll
  for (int z = 0; z < SPLITK1; z++) {
    short4v v = *(const short4v*)(Pb + ((size_t)z << 20) + elem);
    s0 += __uint_as_float(((unsigned)(unsigned short)v[0]) << 16);
    s1 += __uint_as_float(((unsigned)(unsigned short)v[1]) << 16);
    s2 += __uint_as_float(((unsigned)(unsigned short)v[2]) << 16);
    s3 += __uint_as_float(((unsigned)(unsigned short)v[3]) << 16);
  }
  float bv = bias[n];
  int m = m4 * 4;
  O[(size_t)(m + 0) * HID + n] = __float2bfloat16(fmaxf(s0 + bv, 0.0f));
  O[(size_t)(m + 1) * HID + n] = __float2bfloat16(fmaxf(s1 + bv, 0.0f));
  O[(size_t)(m + 2) * HID + n] = __float2bfloat16(fmaxf(s2 + bv, 0.0f));
  O[(size_t)(m + 3) * HID + n] = __float2bfloat16(fmaxf(s3 + bv, 0.0f));
}

// ===================== GEMM2 + fused head partial =========================
// H2 = relu(H1b @ W2T^T + b2) computed per 128x128 tile (full K=1024, NO
// split-K, f32 accum), kept in LDS only; then multiplied by head weights
// (wc|wr staged in LDS) -> per-block partial Ypart[nb][1024 rows][16].
// H2 never touches HBM; 16.8MB partial roundtrip + 57MB weight re-read gone.
// Triple-buffered counted-vmcnt pipeline identical in form to k_gemm1.
#define G2_NKT  16
#define G2_ABUF 8192            // 128*64 bf16 elems
#define G2_BUFE 16384           // A + B per buffer (32 KB)
#define H2P     129             // f32 pitch: bank = (row+k)%32 -> 2-way free

__global__ __launch_bounds__(256, 1) void k_gemm2h(const __hip_bfloat16* __restrict__ A,
                                                   const __hip_bfloat16* __restrict__ BT,
                                                   const float* __restrict__ b2,
                                                   const float* __restrict__ wc,
                                                   const float* __restrict__ wr,
                                                   float* __restrict__ Ypart) {
  __shared__ __align__(16) char smem[3 * G2_BUFE * 2];   // 96 KB, unioned
  __hip_bfloat16* slds = (__hip_bfloat16*)smem;          // K-loop stage bufs
  float* h2 = (float*)smem;                              // [128][H2P] 66 KB
  float* wh = (float*)(smem + 128 * H2P * 4);            // [128][14]   7 KB
  const int m0 = (blockIdx.x >> 3) * 128;
  const int nb = blockIdx.x & 7;
  const int n0 = nb * 128;
  const int tid = threadIdx.x;
  const int wave = tid >> 6, lane = tid & 63;
  const int wm = (wave & 1) * 64, wn = (wave >> 1) * 64;
  const int lm = lane & 15, quad = lane >> 4;

  f32x4f acc[4][4] = {};

  auto stage = [&](int kt, int sb) {
    const int kcol = kt * 64;
    __hip_bfloat16* lb = slds + sb * G2_BUFE;
#pragma unroll
    for (int u = 0; u < 4; ++u) {              // A: 1024 granules / 256 thr
      int idx = tid + u * 256;
      int r = idx >> 3, g = (idx & 7) ^ (r & 7);
      gld_lds16(A + (size_t)(m0 + r) * HID + kcol + g * 8, lb + idx * 8);
    }
#pragma unroll
    for (int u = 0; u < 4; ++u) {              // B: 1024 granules / 256 thr
      int idx = tid + u * 256;
      int r = idx >> 3, g = (idx & 7) ^ (r & 7);
      gld_lds16(BT + (size_t)(n0 + r) * HID + kcol + g * 8, lb + G2_ABUF + idx * 8);
    }
  };

  stage(0, 0);
  stage(1, 1);
  asm volatile("s_waitcnt vmcnt(8)" ::: "memory");   // S(0) resident, S(1) flying
  __builtin_amdgcn_s_barrier();

  int buf = 0;
  for (int kt = 0; kt < G2_NKT; ++kt) {
    int sb = buf + 2; if (sb >= 3) sb -= 3;
    if (kt + 2 < G2_NKT) stage(kt + 2, sb);
    const __hip_bfloat16* Ab = slds + buf * G2_BUFE;
    const __hip_bfloat16* Bb = Ab + G2_ABUF;
    bf16x8f af[4][2], bf[4][2];
#pragma unroll
    for (int i = 0; i < 4; ++i)
#pragma unroll
      for (int s = 0; s < 2; ++s)
        af[i][s] = *(const bf16x8f*)(Ab + (wm + i * 16 + lm) * 64 +
                                     (((s << 2) + quad) ^ (lm & 7)) * 8);
#pragma unroll
    for (int j = 0; j < 4; ++j)
#pragma unroll
      for (int s = 0; s < 2; ++s)
        bf[j][s] = *(const bf16x8f*)(Bb + (wn + j * 16 + lm) * 64 +
                                     (((s << 2) + quad) ^ (lm & 7)) * 8);
    __builtin_amdgcn_s_setprio(1);
#pragma unroll
    for (int s = 0; s < 2; ++s)
#pragma unroll
      for (int i = 0; i < 4; ++i)
#pragma unroll
        for (int j = 0; j < 4; ++j)
          acc[i][j] = __builtin_amdgcn_mfma_f32_16x16x32_bf16(af[i][s], bf[j][s], acc[i][j], 0, 0, 0);
    __builtin_amdgcn_s_setprio(0);
    if (kt < G2_NKT - 1) {
      if (kt < G2_NKT - 2) asm volatile("s_waitcnt vmcnt(8)" ::: "memory");
      else                 asm volatile("s_waitcnt vmcnt(0)" ::: "memory");
      __builtin_amdgcn_s_barrier();
    }
    buf = (buf == 2) ? 0 : buf + 1;
  }
  __syncthreads();      // all ds_reads of stage bufs done before LDS reuse

  // ---- bias + relu -> h2[128][H2P] f32 (C/D map: row=wm+i*16+quad*4+reg,
  //      col=wn+j*16+lm)
  float bb[4];
#pragma unroll
  for (int j = 0; j < 4; ++j) bb[j] = b2[n0 + wn + j * 16 + lm];
#pragma unroll
  for (int i = 0; i < 4; ++i)
#pragma unroll
    for (int j = 0; j < 4; ++j) {
      int col = wn + j * 16 + lm;
#pragma unroll
      for (int r = 0; r < 4; ++r) {
        int row = wm + i * 16 + quad * 4 + r;
        h2[row * H2P + col] = fmaxf(acc[i][j][r] + bb[j], 0.0f);
      }
    }
  // ---- stage head weights wh[128 local n][14]
  for (int idx = tid; idx < 128 * 14; idx += 256) {
    int nl = idx / 14, j = idx - nl * 14;
    wh[idx] = (j < 2) ? wc[(size_t)(n0 + nl) * 2 + j]
                      : wr[(size_t)(n0 + nl) * 12 + (j - 2)];
  }
  __syncthreads();
  // ---- head partial: thread (row = tid&127, half = tid>>7) -> 7 outputs
  int rrow = tid & 127, j0 = (tid >> 7) * 7;
  float s[7] = {};
#pragma unroll 4
  for (int k = 0; k < 128; ++k) {
    float h = h2[rrow * H2P + k];
    const float* w = wh + k * 14 + j0;
#pragma unroll
    for (int j = 0; j < 7; ++j) s[j] += h * w[j];
  }
  float* yp = Ypart + ((size_t)nb * NSEL + m0 + rrow) * 16 + j0;
#pragma unroll
  for (int j = 0; j < 7; ++j) yp[j] = s[j];
}

// ---------------- reduce head partials + biases -> losses (single block)
__global__ __launch_bounds__(1024) void k_head_loss(const float* __restrict__ Ypart,
                                                    const float* __restrict__ bc,
                                                    const float* __restrict__ br,
                                                    const int* __restrict__ sel_labels,
                                                    const float* __restrict__ T,
                                                    float* __restrict__ out) {
  __shared__ float sc[1024];
  __shared__ float sr[1024];
  int n = threadIdx.x;
  float y[14];
#pragma unroll
  for (int j = 0; j < 14; ++j) y[j] = (j < 2) ? bc[j] : br[j - 2];
#pragma unroll
  for (int nb = 0; nb < 8; ++nb) {
    const float* p = Ypart + ((size_t)nb * NSEL + n) * 16;
    float4 v0 = *(const float4*)(p + 0);
    float4 v1 = *(const float4*)(p + 4);
    float4 v2 = *(const float4*)(p + 8);
    float2 v3 = *(const float2*)(p + 12);
    y[0] += v0.x; y[1] += v0.y; y[2] += v0.z; y[3] += v0.w;
    y[4] += v1.x; y[5] += v1.y; y[6] += v1.z; y[7] += v1.w;
    y[8] += v2.x; y[9] += v2.y; y[10] += v2.z; y[11] += v2.w;
    y[12] += v3.x; y[13] += v3.y;
  }
  int lb = sel_labels[n];
  float mx = fmaxf(y[0], y[1]);
  float lse = mx + logf(expf(y[0] - mx) + expf(y[1] - mx));
  float ce = lse - (lb ? y[1] : y[0]);
  float reg = 0.0f;
  if (lb > 0) {
    const float beta = 1.0f / 9.0f;
    const float* t = T + (size_t)n * 6;
#pragma unroll
    for (int j = 0; j < 6; j++) {
      float d = fabsf(y[2 + lb * 6 + j] - t[j]);
      reg += (d < beta) ? (0.5f * d * d / beta) : (d - 0.5f * beta);
    }
  }
  sc[n] = ce; sr[n] = reg;
  __syncthreads();
  for (int sft = 512; sft > 0; sft >>= 1) {
    if (n < sft) { sc[n] += sc[n + sft]; sr[n] += sr[n + sft]; }
    __syncthreads();
  }
  if (n == 0) {
    out[0] = sc[0] * (1.0f / 1024.0f);
    out[1] = sr[0] * (1.0f / 1024.0f);
  }
}

// ------------------------------------------------------------------ launch
extern "C" void kernel_launch(void* const* d_in, const int* in_sizes, int n_in,
                              void* d_out, int out_size, void* d_ws, size_t ws_size,
                              hipStream_t stream) {
  const float* features  = (const float*)d_in[0];
  const float* proposals = (const float*)d_in[1];
  const float* gt_boxes  = (const float*)d_in[2];
  const int*   gt_labels = (const int*)d_in[3];
  const float* gt_ell    = (const float*)d_in[4];
  const float* w1 = (const float*)d_in[5];
  const float* b1 = (const float*)d_in[6];
  const float* w2 = (const float*)d_in[7];
  const float* b2 = (const float*)d_in[8];
  const float* wc = (const float*)d_in[9];
  const float* bc = (const float*)d_in[10];
  const float* wr = (const float*)d_in[11];
  const float* br = (const float*)d_in[12];
  float* out = (float*)d_out;

  char* ws = (char*)d_ws;
  size_t off = 0;
  auto take = [&](size_t bytes) -> void* {
    void* p = ws + off;
    off = (off + bytes + 255) & ~(size_t)255;
    return p;
  };
  // Pb (8 slabs x 2 MiB used; 16 reserved for layout stability); featT aliases.
  __hip_bfloat16* Pb = (__hip_bfloat16*)take((size_t)16 * (1 << 20) * 2);      // 33.5 MB
  __hip_bfloat16* featT = Pb;                                                  // alias
  __hip_bfloat16* Xb  = (__hip_bfloat16*)take((size_t)NSEL * K1P * 2);         // 26.2 MB
  __hip_bfloat16* W1T = (__hip_bfloat16*)take((size_t)HID * K1P * 2);          // 26.2 MB
  __hip_bfloat16* W2T = (__hip_bfloat16*)take((size_t)HID * HID * 2);          // 2.1 MB
  __hip_bfloat16* H1b = (__hip_bfloat16*)take((size_t)NSEL * HID * 2);         // 2.1 MB
  float* Ypart     = (float*)take((size_t)8 * NSEL * 16 * 4);                  // 524 KB
  int*   matches   = (int*)take((size_t)B_IMG * NPROPS * 4);
  int*   plab      = (int*)take((size_t)B_IMG * NPROPS * 4);
  float* prio      = (float*)take((size_t)B_IMG * NPROPS * 4);
  float* sel_boxes = (float*)take((size_t)NSEL * 4 * 4);
  int*   sel_lab   = (int*)take((size_t)NSEL * 4);
  float* targets   = (float*)take((size_t)NSEL * 6 * 4);

  k_pre<<<PRE_TOTAL, 256, 0, stream>>>(proposals, gt_boxes, gt_labels, features,
                                       w1, w2, prio, plab, matches,
                                       featT, W1T, W2T, Xb);
  k_select<<<dim3(NPROPS / 4, B_IMG), 256, 0, stream>>>(prio, proposals, gt_boxes,
                                                        matches, plab, gt_ell,
                                                        sel_boxes, sel_lab, targets);
  k_roialign<<<dim3(NSEL, POOL), 256, 0, stream>>>(featT, sel_boxes, Xb);

  // GEMM1: 256x128 tile, BK=64, triple-buffered counted-vmcnt, split-K=8
  k_gemm1<<<256, 512, 0, stream>>>(Xb, W1T, Pb);
  k_reduce16<<<1024, 256, 0, stream>>>(Pb, b1, H1b);
  // GEMM2 + head partial: 64 blocks, 128x128 tile, full-K f32, fused GEMV
  k_gemm2h<<<64, 256, 0, stream>>>(H1b, W2T, b2, wc, wr, Ypart);
  // reduce partials + losses (single block)
  k_head_loss<<<1, 1024, 0, stream>>>(Ypart, bc, br, sel_lab, targets, out);
}

// Round 4
// 237.253 us; speedup vs baseline: 1.0859x; 1.0268x over previous
//
#include <hip/hip_runtime.h>
#include <hip/hip_bf16.h>
#include <math.h>

#define B_IMG   2
#define N_PROP  2000
#define N_GT    16
#define NPROPS  2016        // N_PROP + N_GT
#define C_FEAT  256
#define H_FEAT  128
#define W_FEAT  128
#define HWF     (H_FEAT*W_FEAT)
#define POOL    7
#define BPI     512
#define NPOSMAX 128
#define NSEL    (B_IMG*BPI)     // 1024
#define K1      (C_FEAT*POOL*POOL)  // 12544
#define K1P     12800           // K1 padded to 16*800
#define HID     1024
#define NHEAD   14
#define SPLITK1 8               // KC = 1600 (pipelined GEMM1)

typedef short bf16x8f __attribute__((ext_vector_type(8)));
typedef float f32x4f  __attribute__((ext_vector_type(4)));
typedef short short4v __attribute__((ext_vector_type(4)));

// ---------------------------------------------------------------- threefry
__device__ __forceinline__ void threefry2x32(unsigned k0, unsigned k1,
                                             unsigned& x0, unsigned& x1) {
  unsigned ks[3] = {k0, k1, k0 ^ k1 ^ 0x1BD11BDAu};
  const int R0[4] = {13, 15, 26, 6};
  const int R1[4] = {17, 29, 16, 24};
  x0 += ks[0]; x1 += ks[1];
#pragma unroll
  for (int g = 0; g < 5; g++) {
    const int* rot = (g & 1) ? R1 : R0;
#pragma unroll
    for (int r = 0; r < 4; r++) {
      x0 += x1;
      x1 = (x1 << rot[r]) | (x1 >> (32 - rot[r]));
      x1 ^= x0;
    }
    x0 += ks[(g + 1) % 3];
    x1 += ks[(g + 2) % 3] + (unsigned)(g + 1);
  }
}

// ---------------- mega-prologue: sample(2) | transpose(2048) | castT1(3136)
//                  | castT0(256) | pad(512)  — blockIdx-range dispatch
#define PRE_SAMPLE   2
#define PRE_TRANS    (PRE_SAMPLE + 2048)
#define PRE_CAST1    (PRE_TRANS + 3136)
#define PRE_CAST0    (PRE_CAST1 + 256)
#define PRE_TOTAL    (PRE_CAST0 + 512)

__global__ __launch_bounds__(256) void k_pre(const float* __restrict__ proposals,
                                             const float* __restrict__ gt_boxes,
                                             const int* __restrict__ gt_labels,
                                             const float* __restrict__ features,
                                             const float* __restrict__ w1,
                                             const float* __restrict__ w2,
                                             float* __restrict__ prio,
                                             int* __restrict__ plab,
                                             int* __restrict__ matches,
                                             __hip_bfloat16* __restrict__ featT,
                                             __hip_bfloat16* __restrict__ W1T,
                                             __hip_bfloat16* __restrict__ W2T,
                                             __hip_bfloat16* __restrict__ Xb) {
  __shared__ __align__(16) char smem[20800];
  int bid = blockIdx.x;
  int tid = threadIdx.x;
  if (bid < PRE_SAMPLE) {
    // ---------------- sample: rand + IoU match + positive-rank priorities
    float* rs    = (float*)smem;              // 2016
    float* pos_r = (float*)(smem + 8064);     // 2016
    short* pos_i = (short*)(smem + 16128);    // 2016
    float* gtb   = (float*)(smem + 20160);    // 64
    int*   gtl   = (int*)(smem + 20416);      // 16
    int*   cnt   = (int*)(smem + 20480);
    int b = bid;
    int base = b * NPROPS;
    if (tid == 0) *cnt = 0;
    if (tid < N_GT * 4) gtb[tid] = gt_boxes[b * N_GT * 4 + tid];
    if (tid < N_GT) gtl[tid] = gt_labels[b * N_GT + tid];
    __syncthreads();
    for (int i = tid; i < NPROPS; i += 256) {
      unsigned x0 = 0u, x1 = (unsigned)(base + i);
      threefry2x32(0u, 42u, x0, x1);
      unsigned bits = x0 ^ x1;
      float r = __uint_as_float((bits >> 9) | 0x3F800000u) - 1.0f;
      rs[i] = r;
      float p0, p1, p2, p3;
      if (i < N_PROP) {
        const float4 v = *(const float4*)(proposals + ((size_t)b * N_PROP + i) * 4);
        p0 = v.x; p1 = v.y; p2 = v.z; p3 = v.w;
      } else {
        const float* g = &gtb[(i - N_PROP) * 4];
        p0 = g[0]; p1 = g[1]; p2 = g[2]; p3 = g[3];
      }
      float a2 = (p2 - p0) * (p3 - p1);
      float best = -1.0f; int bg = 0;
#pragma unroll
      for (int g = 0; g < N_GT; g++) {
        float g0 = gtb[g*4], g1 = gtb[g*4+1], g2 = gtb[g*4+2], g3 = gtb[g*4+3];
        float a1 = (g2 - g0) * (g3 - g1);
        float wx = fmaxf(fminf(g2, p2) - fmaxf(g0, p0), 0.0f);
        float wy = fmaxf(fminf(g3, p3) - fmaxf(g1, p1), 0.0f);
        float inter = wx * wy;
        float iou = inter / (a1 + a2 - inter);
        if (iou > best) { best = iou; bg = g; }
      }
      matches[base + i] = bg;
      int lab = (best < 0.5f) ? 0 : gtl[bg];
      plab[base + i] = lab;
      if (lab > 0) {
        int s = atomicAdd(cnt, 1);
        pos_i[s] = (short)i; pos_r[s] = r;
      }
    }
    __syncthreads();
    int P = *cnt;
    for (int s = tid; s < P; s += 256) {
      int i = pos_i[s]; float ri = pos_r[s];
      int ch = 0;
      for (int j = 0; j < P; j++) {
        float rj = pos_r[j]; int ij = pos_i[j];
        ch += (rj > ri || (rj == ri && ij < i)) ? 1 : 0;
      }
      rs[i] = (ch < NPOSMAX) ? (ri + 2.0f) : -1000000000.0f;
    }
    __syncthreads();
    for (int i = tid; i < NPROPS; i += 256) prio[base + i] = rs[i];
  } else if (bid < PRE_TRANS) {
    // ---------------- NCHW -> NHWC bf16, 64x64 tiles
    float (*tile)[65] = (float(*)[65])smem;
    int t = bid - PRE_SAMPLE;
    int b = t >> 10;
    int rem = t & 1023;
    int c0 = (rem >> 8) * 64;
    int s0 = (rem & 255) * 64;
    const float* src = features + (size_t)b * C_FEAT * HWF;
    __hip_bfloat16* dst = featT + (size_t)b * HWF * C_FEAT;
    int hw4 = (tid & 15) * 4, cr = tid >> 4;
#pragma unroll
    for (int p = 0; p < 4; p++) {
      int c = cr + p * 16;
      float4 v = *(const float4*)(src + (size_t)(c0 + c) * HWF + s0 + hw4);
      tile[hw4 + 0][c] = v.x; tile[hw4 + 1][c] = v.y;
      tile[hw4 + 2][c] = v.z; tile[hw4 + 3][c] = v.w;
    }
    __syncthreads();
    int c4 = (tid & 15) * 4, hr = tid >> 4;
#pragma unroll
    for (int p = 0; p < 4; p++) {
      int hw = hr + p * 16;
      __hip_bfloat16 o[4] = {__float2bfloat16(tile[hw][c4]), __float2bfloat16(tile[hw][c4+1]),
                             __float2bfloat16(tile[hw][c4+2]), __float2bfloat16(tile[hw][c4+3])};
      *(short4v*)(dst + (size_t)(s0 + hw) * C_FEAT + c0 + c4) = *(short4v*)o;
    }
  } else if (bid < PRE_CAST1) {
    // ---------------- w1 cast: fp32 [c*49+p][N] -> bf16 [N][p*256+c]
    float (*tile)[65] = (float(*)[65])smem;
    int t = bid - PRE_TRANS;
    int p = t >> 6;
    int rem = t & 63;
    int c0 = (rem & 3) * 64;
    int n0 = (rem >> 2) * 64;
    int n4 = (tid & 15) * 4, ig = tid >> 4;   // 16 row-groups
#pragma unroll
    for (int i = ig; i < 64; i += 16) {
      float4 v = *(const float4*)(w1 + (size_t)((c0 + i) * 49 + p) * HID + n0 + n4);
      tile[i][n4] = v.x; tile[i][n4 + 1] = v.y;
      tile[i][n4 + 2] = v.z; tile[i][n4 + 3] = v.w;
    }
    __syncthreads();
    int c4 = (tid & 15) * 4;
#pragma unroll
    for (int i = ig; i < 64; i += 16) {
      __hip_bfloat16 o[4] = {__float2bfloat16(tile[c4][i]), __float2bfloat16(tile[c4 + 1][i]),
                             __float2bfloat16(tile[c4 + 2][i]), __float2bfloat16(tile[c4 + 3][i])};
      *(short4v*)(W1T + (size_t)(n0 + i) * K1P + p * 256 + c0 + c4) = *(short4v*)o;
    }
  } else if (bid < PRE_CAST0) {
    // ---------------- w2 cast: fp32 [K][N] -> bf16 [N][K], vectorized
    float (*tile)[65] = (float(*)[65])smem;
    int t = bid - PRE_CAST1;
    int c0 = (t & 15) * 64;
    int n0 = (t >> 4) * 64;
    int n4 = (tid & 15) * 4, ig = tid >> 4;
#pragma unroll
    for (int i = ig; i < 64; i += 16) {
      float4 v = *(const float4*)(w2 + (size_t)(c0 + i) * HID + n0 + n4);
      tile[i][n4] = v.x; tile[i][n4 + 1] = v.y;
      tile[i][n4 + 2] = v.z; tile[i][n4 + 3] = v.w;
    }
    __syncthreads();
    int c4 = (tid & 15) * 4;
#pragma unroll
    for (int i = ig; i < 64; i += 16) {
      __hip_bfloat16 o[4] = {__float2bfloat16(tile[c4][i]), __float2bfloat16(tile[c4 + 1][i]),
                             __float2bfloat16(tile[c4 + 2][i]), __float2bfloat16(tile[c4 + 3][i])};
      *(short4v*)(W2T + (size_t)(n0 + i) * HID + c0 + c4) = *(short4v*)o;
    }
  } else {
    // ---------------- zero K-pad cols K1..K1P of Xb / W1T
    int t = bid - PRE_CAST0;        // 0..511
    __hip_bfloat16* buf = (t >> 8) ? W1T : Xb;
    int tt = (t & 255) * 256 + tid;
    int row = tt >> 6;
    int col4 = (tt & 63) << 2;
    short4v z = {0, 0, 0, 0};
    *(short4v*)(buf + (size_t)row * K1P + K1 + col4) = z;
  }
}

// ------------------------------------------------- select + gather + encode
__global__ __launch_bounds__(256) void k_select(const float* __restrict__ prio,
    const float* __restrict__ proposals, const float* __restrict__ gt_boxes,
    const int* __restrict__ matches, const int* __restrict__ plab,
    const float* __restrict__ gt_ell,
    float* __restrict__ sel_boxes, int* __restrict__ sel_labels,
    float* __restrict__ targets) {
  int tid = threadIdx.x;
  int wave = tid >> 6, lane = tid & 63;
  int b = blockIdx.y;
  int base = b * NPROPS;
  int i = blockIdx.x * 4 + wave;
  float pi = prio[base + i];
  int rank = 0;
  for (int j = lane; j < NPROPS; j += 64) {
    float pj = prio[base + j];
    rank += (pj > pi || (pj == pi && j < i)) ? 1 : 0;
  }
#pragma unroll
  for (int off = 32; off > 0; off >>= 1) rank += __shfl_down(rank, off);
  if (lane != 0 || rank >= BPI) return;
  int slot = b * BPI + rank;
  float p0, p1, p2, p3;
  if (i < N_PROP) {
    const float* p = proposals + ((size_t)b * N_PROP + i) * 4;
    p0 = p[0]; p1 = p[1]; p2 = p[2]; p3 = p[3];
  } else {
    const float* p = gt_boxes + ((size_t)b * N_GT + (i - N_PROP)) * 4;
    p0 = p[0]; p1 = p[1]; p2 = p[2]; p3 = p[3];
  }
  sel_boxes[slot * 4 + 0] = p0;
  sel_boxes[slot * 4 + 1] = p1;
  sel_boxes[slot * 4 + 2] = p2;
  sel_boxes[slot * 4 + 3] = p3;
  int lb = plab[base + i];
  sel_labels[slot] = lb;
  int m = matches[base + i];
  const float* e = gt_ell + ((size_t)b * N_GT + m) * 5;
  float ea = e[0], eb = e[1], ex = e[2], ey = e[3], eth = e[4];
  float w = fmaxf(p2 - p0, 1.0f), h = fmaxf(p3 - p1, 1.0f);
  float cx = 0.5f * (p0 + p2), cy = 0.5f * (p1 + p3);
  float* t = targets + (size_t)slot * 6;
  t[0] = (ex - cx) / w;
  t[1] = (ey - cy) / h;
  t[2] = logf(fmaxf(2.0f * ea, 0.001f) / w);
  t[3] = logf(fmaxf(2.0f * eb, 0.001f) / h);
  t[4] = sinf(2.0f * eth);
  t[5] = cosf(2.0f * eth);
}

// ---------------- roi align (bf16 feat), b128 loads, 32 lanes x 8ch per px
__global__ __launch_bounds__(256) void k_roialign(const __hip_bfloat16* __restrict__ featT,
                                                  const float* __restrict__ sel_boxes,
                                                  __hip_bfloat16* __restrict__ X) {
  int n = blockIdx.x;
  int py = blockIdx.y;
  int t = threadIdx.x;
  int px = t >> 5;            // 0..7 (half-wave granularity)
  int lane32 = t & 31;
  int c = lane32 << 3;        // 8 channels / lane, 16B
  int b = n >> 9;
  const float* bx = sel_boxes + (size_t)n * 4;
  float x1 = bx[0] * 0.125f, y1 = bx[1] * 0.125f;
  float x2 = bx[2] * 0.125f, y2 = bx[3] * 0.125f;
  float bw = fmaxf(x2 - x1, 1.0f) / 7.0f;
  float bh = fmaxf(y2 - y1, 1.0f) / 7.0f;
  if (px >= 7) return;        // upper half of wave 3 idle (1/8)
  const __hip_bfloat16* base = featT + (size_t)b * HWF * C_FEAT;
  int y0A[2]; float lyA[2];
#pragma unroll
  for (int sy = 0; sy < 2; sy++) {
    float off = ((float)(py * 2 + sy) + 0.5f) * 0.5f;
    float ys = fminf(fmaxf(y1 + off * bh, 0.0f), 127.0f);
    int y0 = (int)fminf(fmaxf(floorf(ys), 0.0f), 126.0f);
    y0A[sy] = y0; lyA[sy] = ys - (float)y0;
  }
  float acc[8] = {};
#pragma unroll
  for (int sx = 0; sx < 2; sx++) {
    float off = ((float)(px * 2 + sx) + 0.5f) * 0.5f;
    float xs = fminf(fmaxf(x1 + off * bw, 0.0f), 127.0f);
    int x0 = (int)fminf(fmaxf(floorf(xs), 0.0f), 126.0f);
    float lx = xs - (float)x0;
#pragma unroll
    for (int sy = 0; sy < 2; sy++) {
      int y0 = y0A[sy]; float ly = lyA[sy];
      const __hip_bfloat16* p = base + ((size_t)(y0 * W_FEAT + x0)) * C_FEAT + c;
      bf16x8f s00 = *(const bf16x8f*)p;
      bf16x8f s01 = *(const bf16x8f*)(p + C_FEAT);
      bf16x8f s10 = *(const bf16x8f*)(p + W_FEAT * C_FEAT);
      bf16x8f s11 = *(const bf16x8f*)(p + W_FEAT * C_FEAT + C_FEAT);
      float w00 = (1.0f - ly) * (1.0f - lx), w01 = (1.0f - ly) * lx;
      float w10 = ly * (1.0f - lx), w11 = ly * lx;
#pragma unroll
      for (int q = 0; q < 8; q++) {
        float v00 = __uint_as_float(((unsigned)(unsigned short)s00[q]) << 16);
        float v01 = __uint_as_float(((unsigned)(unsigned short)s01[q]) << 16);
        float v10 = __uint_as_float(((unsigned)(unsigned short)s10[q]) << 16);
        float v11 = __uint_as_float(((unsigned)(unsigned short)s11[q]) << 16);
        acc[q] += v00 * w00 + v01 * w01 + v10 * w10 + v11 * w11;
      }
    }
  }
  __hip_bfloat16 o[8];
#pragma unroll
  for (int q = 0; q < 8; q++) o[q] = __float2bfloat16(acc[q] * 0.25f);
  *(bf16x8f*)&X[(size_t)n * K1P + (size_t)(py * 7 + px) * C_FEAT + c] = *(bf16x8f*)o;
}

// ------------------------------------------------------- global->LDS helper
__device__ __forceinline__ void gld_lds16(const __hip_bfloat16* g, __hip_bfloat16* l) {
  __builtin_amdgcn_global_load_lds(
      (const __attribute__((address_space(1))) void*)g,
      (__attribute__((address_space(3))) void*)l, 16, 0, 0);
}

// ===================== GEMM1: triple-buffered counted-vmcnt pipeline ======
// C[1024x1024] = Xb[1024xK1P] * W1T[1024xK1P]^T, split-K=8 (KC=1600).
// BM=256 BN=128 BK=64, 512 thr (8 waves of 64x64), LDS 3 x 48KB = 144KB.
#define G1_KC   1600
#define G1_NKT  25
#define G1_ABUF 16384   // 256*64 bf16
#define G1_BUFE 24576   // A(16384) + B(8192) per buffer

__global__ __launch_bounds__(512, 1) void k_gemm1(const __hip_bfloat16* __restrict__ A,
                                                  const __hip_bfloat16* __restrict__ BT,
                                                  __hip_bfloat16* __restrict__ Pb) {
  __shared__ __align__(16) __hip_bfloat16 lds[3 * G1_BUFE];  // 144 KiB
  const int lin = blockIdx.x;
  // pair = (m,kz): constant on each XCD (bits0-2 + bits6-7); n in bits3-5
  const int pair = (lin & 7) + ((lin >> 6) << 3);   // 0..31
  const int m0 = (pair & 3) * 256;
  const int kz = pair >> 2;
  const int n0 = ((lin >> 3) & 7) * 128;
  const int kbeg = kz * G1_KC;
  const int tid = threadIdx.x;
  const int wave = tid >> 6, lane = tid & 63;
  const int wm = (wave & 3) * 64, wn = (wave >> 2) * 64;
  const int lm = lane & 15, quad = lane >> 4;

  f32x4f acc[4][4] = {};

  auto stage = [&](int kt, int sb) {
    const int kcol = kbeg + kt * 64;
    __hip_bfloat16* lb = lds + sb * G1_BUFE;
#pragma unroll
    for (int u = 0; u < 4; ++u) {              // A: 2048 granules / 512 thr
      int idx = tid + u * 512;
      int r = idx >> 3, g = (idx & 7) ^ (r & 7);
      gld_lds16(A + (size_t)(m0 + r) * K1P + kcol + g * 8, lb + idx * 8);
    }
#pragma unroll
    for (int u = 0; u < 2; ++u) {              // B: 1024 granules / 512 thr
      int idx = tid + u * 512;
      int r = idx >> 3, g = (idx & 7) ^ (r & 7);
      gld_lds16(BT + (size_t)(n0 + r) * K1P + kcol + g * 8, lb + G1_ABUF + idx * 8);
    }
  };

  stage(0, 0);
  stage(1, 1);
  asm volatile("s_waitcnt vmcnt(6)" ::: "memory");   // S(0) resident, S(1) flying
  __builtin_amdgcn_s_barrier();

  int buf = 0;
  for (int kt = 0; kt < G1_NKT; ++kt) {
    int sb = buf + 2; if (sb >= 3) sb -= 3;
    if (kt + 2 < G1_NKT) stage(kt + 2, sb);
    const __hip_bfloat16* Ab = lds + buf * G1_BUFE;
    const __hip_bfloat16* Bb = Ab + G1_ABUF;
    bf16x8f af[4][2], bf[4][2];
#pragma unroll
    for (int i = 0; i < 4; ++i)
#pragma unroll
      for (int s = 0; s < 2; ++s)
        af[i][s] = *(const bf16x8f*)(Ab + (wm + i * 16 + lm) * 64 +
                                     (((s << 2) + quad) ^ (lm & 7)) * 8);
#pragma unroll
    for (int j = 0; j < 4; ++j)
#pragma unroll
      for (int s = 0; s < 2; ++s)
        bf[j][s] = *(const bf16x8f*)(Bb + (wn + j * 16 + lm) * 64 +
                                     (((s << 2) + quad) ^ (lm & 7)) * 8);
    __builtin_amdgcn_s_setprio(1);
#pragma unroll
    for (int s = 0; s < 2; ++s)
#pragma unroll
      for (int i = 0; i < 4; ++i)
#pragma unroll
        for (int j = 0; j < 4; ++j)
          acc[i][j] = __builtin_amdgcn_mfma_f32_16x16x32_bf16(af[i][s], bf[j][s], acc[i][j], 0, 0, 0);
    __builtin_amdgcn_s_setprio(0);
    if (kt < G1_NKT - 1) {
      if (kt < G1_NKT - 2) asm volatile("s_waitcnt vmcnt(6)" ::: "memory");
      else                 asm volatile("s_waitcnt vmcnt(0)" ::: "memory");
      __builtin_amdgcn_s_barrier();
    }
    buf = (buf == 2) ? 0 : buf + 1;
  }

  // packed bf16 partials, identical layout to k_reduce16 ABI
  int tileoff = ((m0 >> 8) * 8 + (n0 >> 7)) * 32768;
  __hip_bfloat16* dst = Pb + ((size_t)kz << 20) + tileoff + wave * 4096 + lane * 4;
#pragma unroll
  for (int i = 0; i < 4; ++i)
#pragma unroll
    for (int j = 0; j < 4; ++j) {
      __hip_bfloat16 o[4] = {__float2bfloat16(acc[i][j][0]), __float2bfloat16(acc[i][j][1]),
                             __float2bfloat16(acc[i][j][2]), __float2bfloat16(acc[i][j][3])};
      *(short4v*)(dst + (i * 4 + j) * 256) = *(short4v*)o;
    }
}

// ---------------- reduce GEMM1 packed partials + bias + relu -> H1b (bf16)
__global__ __launch_bounds__(256) void k_reduce16(const __hip_bfloat16* __restrict__ Pb,
                                                  const float* __restrict__ bias,
                                                  __hip_bfloat16* __restrict__ O) {
  int m4 = blockIdx.x >> 2;
  int n  = (blockIdx.x & 3) * 256 + threadIdx.x;
  int m0i = m4 >> 6, wavem = (m4 >> 4) & 3, i = (m4 >> 2) & 3, quad = m4 & 3;
  int n0i = n >> 7, wn = (n >> 6) & 1, j = (n >> 4) & 3, lm = n & 15;
  int wave = wavem + wn * 4;
  int elem = (m0i * 8 + n0i) * 32768 + wave * 4096 + (i * 4 + j) * 256 + (quad * 16 + lm) * 4;
  float s0 = 0.0f, s1 = 0.0f, s2 = 0.0f, s3 = 0.0f;
#pragma unroll
  for (int z = 0; z < SPLITK1; z++) {
    short4v v = *(const short4v*)(Pb + ((size_t)z << 20) + elem);
    s0 += __uint_as_float(((unsigned)(unsigned short)v[0]) << 16);
    s1 += __uint_as_float(((unsigned)(unsigned short)v[1]) << 16);
    s2 += __uint_as_float(((unsigned)(unsigned short)v[2]) << 16);
    s3 += __uint_as_float(((unsigned)(unsigned short)v[3]) << 16);
  }
  float bv = bias[n];
  int m = m4 * 4;
  O[(size_t)(m + 0) * HID + n] = __float2bfloat16(fmaxf(s0 + bv, 0.0f));
  O[(size_t)(m + 1) * HID + n] = __float2bfloat16(fmaxf(s1 + bv, 0.0f));
  O[(size_t)(m + 2) * HID + n] = __float2bfloat16(fmaxf(s2 + bv, 0.0f));
  O[(size_t)(m + 3) * HID + n] = __float2bfloat16(fmaxf(s3 + bv, 0.0f));
}

// ===================== GEMM2 + fused head partial + fused loss ============
// H2 = relu(H1b @ W2T^T + b2) per 128x128 tile (full K=1024, f32 accum) in
// LDS only; head GEMV (wc|wr staged in LDS) -> Ypart[nb][1024][16]; the
// LAST of the 64 blocks (device atomic, &63 so poison-safe) reduces the 8
// nb-partials + biases into both losses. 512 thr: 8 waves, wave tile 64x32.
#define G2_NKT  16
#define G2_ABUF 8192            // 128*64 bf16 elems
#define G2_BUFE 16384           // A + B per buffer (32 KB)
#define H2P     129             // f32 pitch: bank = (row+k)%32 -> conflict-free

__global__ __launch_bounds__(512, 1) void k_gemm2h(const __hip_bfloat16* __restrict__ A,
                                                   const __hip_bfloat16* __restrict__ BT,
                                                   const float* __restrict__ b2,
                                                   const float* __restrict__ wc,
                                                   const float* __restrict__ wr,
                                                   float* __restrict__ Ypart,
                                                   const float* __restrict__ bc,
                                                   const float* __restrict__ br,
                                                   const int* __restrict__ sel_labels,
                                                   const float* __restrict__ T,
                                                   float* __restrict__ out,
                                                   int* __restrict__ loss_cnt) {
  __shared__ __align__(16) char smem[3 * G2_BUFE * 2];   // 96 KB, unioned
  __shared__ int lastf;
  __hip_bfloat16* slds = (__hip_bfloat16*)smem;          // K-loop stage bufs
  float* h2 = (float*)smem;                              // [128][H2P] 66 KB
  float* wh = (float*)(smem + 128 * H2P * 4);            // [128][14]   7 KB
  const int m0 = (blockIdx.x >> 3) * 128;
  const int nb = blockIdx.x & 7;
  const int n0 = nb * 128;
  const int tid = threadIdx.x;
  const int wave = tid >> 6, lane = tid & 63;
  const int wm = (wave & 1) * 64, wn = (wave >> 1) * 32;
  const int lm = lane & 15, quad = lane >> 4;

  f32x4f acc[4][2] = {};

  auto stage = [&](int kt, int sb) {
    const int kcol = kt * 64;
    __hip_bfloat16* lb = slds + sb * G2_BUFE;
#pragma unroll
    for (int u = 0; u < 2; ++u) {              // A: 1024 granules / 512 thr
      int idx = tid + u * 512;
      int r = idx >> 3, g = (idx & 7) ^ (r & 7);
      gld_lds16(A + (size_t)(m0 + r) * HID + kcol + g * 8, lb + idx * 8);
    }
#pragma unroll
    for (int u = 0; u < 2; ++u) {              // B: 1024 granules / 512 thr
      int idx = tid + u * 512;
      int r = idx >> 3, g = (idx & 7) ^ (r & 7);
      gld_lds16(BT + (size_t)(n0 + r) * HID + kcol + g * 8, lb + G2_ABUF + idx * 8);
    }
  };

  stage(0, 0);
  stage(1, 1);
  asm volatile("s_waitcnt vmcnt(4)" ::: "memory");   // S(0) resident, S(1) flying
  __builtin_amdgcn_s_barrier();

  int buf = 0;
  for (int kt = 0; kt < G2_NKT; ++kt) {
    int sb = buf + 2; if (sb >= 3) sb -= 3;
    if (kt + 2 < G2_NKT) stage(kt + 2, sb);
    const __hip_bfloat16* Ab = slds + buf * G2_BUFE;
    const __hip_bfloat16* Bb = Ab + G2_ABUF;
    bf16x8f af[4][2], bf[2][2];
#pragma unroll
    for (int i = 0; i < 4; ++i)
#pragma unroll
      for (int s = 0; s < 2; ++s)
        af[i][s] = *(const bf16x8f*)(Ab + (wm + i * 16 + lm) * 64 +
                                     (((s << 2) + quad) ^ (lm & 7)) * 8);
#pragma unroll
    for (int j = 0; j < 2; ++j)
#pragma unroll
      for (int s = 0; s < 2; ++s)
        bf[j][s] = *(const bf16x8f*)(Bb + (wn + j * 16 + lm) * 64 +
                                     (((s << 2) + quad) ^ (lm & 7)) * 8);
    __builtin_amdgcn_s_setprio(1);
#pragma unroll
    for (int s = 0; s < 2; ++s)
#pragma unroll
      for (int i = 0; i < 4; ++i)
#pragma unroll
        for (int j = 0; j < 2; ++j)
          acc[i][j] = __builtin_amdgcn_mfma_f32_16x16x32_bf16(af[i][s], bf[j][s], acc[i][j], 0, 0, 0);
    __builtin_amdgcn_s_setprio(0);
    if (kt < G2_NKT - 1) {
      if (kt < G2_NKT - 2) asm volatile("s_waitcnt vmcnt(4)" ::: "memory");
      else                 asm volatile("s_waitcnt vmcnt(0)" ::: "memory");
      __builtin_amdgcn_s_barrier();
    }
    buf = (buf == 2) ? 0 : buf + 1;
  }
  __syncthreads();      // all ds_reads of stage bufs done before LDS reuse

  // ---- bias + relu -> h2[128][H2P] f32 (C/D map: row=wm+i*16+quad*4+reg,
  //      col=wn+j*16+lm)
  float bb[2];
#pragma unroll
  for (int j = 0; j < 2; ++j) bb[j] = b2[n0 + wn + j * 16 + lm];
#pragma unroll
  for (int i = 0; i < 4; ++i)
#pragma unroll
    for (int j = 0; j < 2; ++j) {
      int col = wn + j * 16 + lm;
#pragma unroll
      for (int r = 0; r < 4; ++r) {
        int row = wm + i * 16 + quad * 4 + r;
        h2[row * H2P + col] = fmaxf(acc[i][j][r] + bb[j], 0.0f);
      }
    }
  // ---- stage head weights wh[128 local n][14]
  for (int idx = tid; idx < 128 * 14; idx += 512) {
    int nl = idx / 14, j = idx - nl * 14;
    wh[idx] = (j < 2) ? wc[(size_t)(n0 + nl) * 2 + j]
                      : wr[(size_t)(n0 + nl) * 12 + (j - 2)];
  }
  __syncthreads();
  // ---- head partial: thread (row = tid&127, jg = tid>>7) -> 4 outputs
  {
    int rrow = tid & 127, jg = tid >> 7;       // jg 0..3
    int j0 = jg * 4, jn = (jg == 3) ? 2 : 4;   // 4,4,4,2 -> 14
    float s[4] = {};
#pragma unroll 4
    for (int k = 0; k < 128; ++k) {
      float h = h2[rrow * H2P + k];
      const float* w = wh + k * 14 + j0;
#pragma unroll
      for (int j = 0; j < 4; ++j) s[j] += h * w[j];
    }
    float* yp = Ypart + ((size_t)nb * NSEL + m0 + rrow) * 16 + j0;
    for (int j = 0; j < jn; ++j) yp[j] = s[j];
  }
  // ---------------- last-block loss (64 blocks; &63 poison-safe)
  __syncthreads();
  if (tid == 0) {
    __threadfence();
    int old = atomicAdd(loss_cnt, 1);
    lastf = ((old & 63) == 63) ? 1 : 0;
  }
  __syncthreads();
  if (!lastf) return;
  __threadfence();
  float* sc = (float*)smem;            // 512 floats
  float* sr = sc + 512;                // 512 floats
  float ce_s = 0.0f, rg_s = 0.0f;
#pragma unroll
  for (int half = 0; half < 2; ++half) {
    int n = tid + half * 512;
    float y[14];
#pragma unroll
    for (int j = 0; j < 14; ++j) y[j] = (j < 2) ? bc[j] : br[j - 2];
#pragma unroll
    for (int nb2 = 0; nb2 < 8; ++nb2) {
      const float* p = Ypart + ((size_t)nb2 * NSEL + n) * 16;
      float4 v0 = *(const float4*)(p + 0);
      float4 v1 = *(const float4*)(p + 4);
      float4 v2 = *(const float4*)(p + 8);
      float2 v3 = *(const float2*)(p + 12);
      y[0] += v0.x; y[1] += v0.y; y[2] += v0.z; y[3] += v0.w;
      y[4] += v1.x; y[5] += v1.y; y[6] += v1.z; y[7] += v1.w;
      y[8] += v2.x; y[9] += v2.y; y[10] += v2.z; y[11] += v2.w;
      y[12] += v3.x; y[13] += v3.y;
    }
    int lb = sel_labels[n];
    float mx = fmaxf(y[0], y[1]);
    float lse = mx + logf(expf(y[0] - mx) + expf(y[1] - mx));
    ce_s += lse - (lb ? y[1] : y[0]);
    if (lb > 0) {
      const float beta = 1.0f / 9.0f;
      const float* t = T + (size_t)n * 6;
#pragma unroll
      for (int j = 0; j < 6; j++) {
        float d = fabsf(y[2 + lb * 6 + j] - t[j]);
        rg_s += (d < beta) ? (0.5f * d * d / beta) : (d - 0.5f * beta);
      }
    }
  }
  sc[tid] = ce_s; sr[tid] = rg_s;
  __syncthreads();
  for (int sft = 256; sft > 0; sft >>= 1) {
    if (tid < sft) { sc[tid] += sc[tid + sft]; sr[tid] += sr[tid + sft]; }
    __syncthreads();
  }
  if (tid == 0) {
    out[0] = sc[0] * (1.0f / 1024.0f);
    out[1] = sr[0] * (1.0f / 1024.0f);
  }
}

// ------------------------------------------------------------------ launch
extern "C" void kernel_launch(void* const* d_in, const int* in_sizes, int n_in,
                              void* d_out, int out_size, void* d_ws, size_t ws_size,
                              hipStream_t stream) {
  const float* features  = (const float*)d_in[0];
  const float* proposals = (const float*)d_in[1];
  const float* gt_boxes  = (const float*)d_in[2];
  const int*   gt_labels = (const int*)d_in[3];
  const float* gt_ell    = (const float*)d_in[4];
  const float* w1 = (const float*)d_in[5];
  const float* b1 = (const float*)d_in[6];
  const float* w2 = (const float*)d_in[7];
  const float* b2 = (const float*)d_in[8];
  const float* wc = (const float*)d_in[9];
  const float* bc = (const float*)d_in[10];
  const float* wr = (const float*)d_in[11];
  const float* br = (const float*)d_in[12];
  float* out = (float*)d_out;

  char* ws = (char*)d_ws;
  size_t off = 0;
  auto take = [&](size_t bytes) -> void* {
    void* p = ws + off;
    off = (off + bytes + 255) & ~(size_t)255;
    return p;
  };
  // Pb (8 slabs x 2 MiB used; 16 reserved for layout stability); featT aliases.
  __hip_bfloat16* Pb = (__hip_bfloat16*)take((size_t)16 * (1 << 20) * 2);      // 33.5 MB
  __hip_bfloat16* featT = Pb;                                                  // alias
  __hip_bfloat16* Xb  = (__hip_bfloat16*)take((size_t)NSEL * K1P * 2);         // 26.2 MB
  __hip_bfloat16* W1T = (__hip_bfloat16*)take((size_t)HID * K1P * 2);          // 26.2 MB
  __hip_bfloat16* W2T = (__hip_bfloat16*)take((size_t)HID * HID * 2);          // 2.1 MB
  __hip_bfloat16* H1b = (__hip_bfloat16*)take((size_t)NSEL * HID * 2);         // 2.1 MB
  float* Ypart     = (float*)take((size_t)8 * NSEL * 16 * 4);                  // 524 KB
  int*   matches   = (int*)take((size_t)B_IMG * NPROPS * 4);
  int*   plab      = (int*)take((size_t)B_IMG * NPROPS * 4);
  float* prio      = (float*)take((size_t)B_IMG * NPROPS * 4);
  float* sel_boxes = (float*)take((size_t)NSEL * 4 * 4);
  int*   sel_lab   = (int*)take((size_t)NSEL * 4);
  float* targets   = (float*)take((size_t)NSEL * 6 * 4);
  int*   loss_cnt  = (int*)take(256);

  k_pre<<<PRE_TOTAL, 256, 0, stream>>>(proposals, gt_boxes, gt_labels, features,
                                       w1, w2, prio, plab, matches,
                                       featT, W1T, W2T, Xb);
  k_select<<<dim3(NPROPS / 4, B_IMG), 256, 0, stream>>>(prio, proposals, gt_boxes,
                                                        matches, plab, gt_ell,
                                                        sel_boxes, sel_lab, targets);
  k_roialign<<<dim3(NSEL, POOL), 256, 0, stream>>>(featT, sel_boxes, Xb);

  // GEMM1: 256x128 tile, BK=64, triple-buffered counted-vmcnt, split-K=8
  k_gemm1<<<256, 512, 0, stream>>>(Xb, W1T, Pb);
  k_reduce16<<<1024, 256, 0, stream>>>(Pb, b1, H1b);
  // GEMM2 + head partial + fused last-block loss: 64 blocks, 512 thr
  k_gemm2h<<<64, 512, 0, stream>>>(H1b, W2T, b2, wc, wr, Ypart,
                                   bc, br, sel_lab, targets, out, loss_cnt);
}